// Round 6
// baseline (364.450 us; speedup 1.0000x reference)
//
#include <hip/hip_runtime.h>
#include <hip/hip_bf16.h>
#include <math.h>

#define NH 32
#define NKV 8
#define HD 64
#define B_ 2
#define S_ 2048
#define E_ 2048
#define M_ 4096   // B_*S_

typedef unsigned short ushort_t;
typedef __attribute__((ext_vector_type(8))) short short8;
typedef __attribute__((ext_vector_type(4))) short short4v;
typedef __attribute__((ext_vector_type(4))) float floatx4;

__device__ inline unsigned short f2bf(float f) {
  unsigned int u = __float_as_uint(f);
  return (unsigned short)((u + 0x7FFFu + ((u >> 16) & 1u)) >> 16);  // RNE
}

__device__ inline float fexp2(float x) {  // raw v_exp_f32 (HW is base-2)
  float r;
  asm("v_exp_f32 %0, %1" : "=v"(r) : "v"(x));
  return r;
}

// async global->LDS, 16B per lane; lds base must be wave-uniform (HW adds lane*16)
__device__ inline void ld_lds16(const void* g, void* l) {
  __builtin_amdgcn_global_load_lds((__attribute__((address_space(1))) void*)g,
                                   (__attribute__((address_space(3))) void*)l, 16, 0, 0);
}

// ---------------- x fp32 -> bf16 ----------------
__global__ __launch_bounds__(256) void cast_x(const float* __restrict__ x,
                                              ushort_t* __restrict__ xb) {
  size_t i = ((size_t)blockIdx.x * 256 + threadIdx.x) * 8;
  float4 a = *(const float4*)(x + i);
  float4 b = *(const float4*)(x + i + 4);
  short8 o;
  o[0] = (short)f2bf(a.x); o[1] = (short)f2bf(a.y);
  o[2] = (short)f2bf(a.z); o[3] = (short)f2bf(a.w);
  o[4] = (short)f2bf(b.x); o[5] = (short)f2bf(b.y);
  o[6] = (short)f2bf(b.z); o[7] = (short)f2bf(b.w);
  *(short8*)(xb + i) = o;
}

// ---------------- transpose (R,C) fp32 -> (C,R) bf16 ----------------
__global__ __launch_bounds__(256) void transpose_w(const float* __restrict__ in,
                                                   ushort_t* __restrict__ out,
                                                   int R, int C) {
  __shared__ float tile[32][33];
  int c0 = blockIdx.x * 32, r0 = blockIdx.y * 32;
  int x = threadIdx.x, y0 = threadIdx.y;  // block (32,8)
  for (int i = 0; i < 4; i++) {
    int r = y0 + i * 8;
    tile[r][x] = in[(size_t)(r0 + r) * C + c0 + x];
  }
  __syncthreads();
  for (int i = 0; i < 4; i++) {
    int r = y0 + i * 8;
    out[(size_t)(c0 + r) * R + r0 + x] = f2bf(tile[x][r]);
  }
}

// ---------------- outv (B,NKV,S,HD) fp32 -> vt TILED (bg, S/64, HD, 64) bf16, swizzled ----
__global__ __launch_bounds__(256) void transpose_v(const float* __restrict__ outv,
                                                   ushort_t* __restrict__ vt) {
  __shared__ float t64[64][65];
  int bg = blockIdx.y;        // 0..15
  int tt = blockIdx.x;        // s-tile 0..31
  int s0 = tt * 64;
  int tid = threadIdx.x;
  size_t ibase = (size_t)bg * S_ * HD + (size_t)s0 * HD;
  for (int i = tid; i < 1024; i += 256) {
    int sr = i >> 4, dc = (i & 15) * 4;
    float4 v = *(const float4*)(outv + ibase + (size_t)sr * HD + dc);
    t64[sr][dc] = v.x; t64[sr][dc + 1] = v.y; t64[sr][dc + 2] = v.z; t64[sr][dc + 3] = v.w;
  }
  __syncthreads();
  size_t obase = ((size_t)bg * 32 + tt) * 4096;  // 64*64 elements per tile
  for (int i = tid; i < 512; i += 256) {
    int d = i >> 3, ss = (i & 7) * 8;
    short8 o;
#pragma unroll
    for (int e = 0; e < 8; e++) o[e] = (short)f2bf(t64[ss + e][d]);
    *(short8*)(vt + obase + d * 64 + (ss ^ ((d & 7) << 3))) = o;
  }
}

// ====== 128x128 / BK=64 GEMM core, 4-buffer depth-3 pipeline, counted vmcnt (T4) ======
// 512 threads = 8 waves (4M x 2N); per-wave C: 32x64 = acc[2][4]. LDS 128 KiB:
// A[4][128][64] + B[4][128][64] bf16, XOR-swizzled 16B chunks (LDS[row][c]=G[row][c^(row&7)]),
// staged via global_load_lds (linear dest, pre-swizzled per-lane source; 4 loads/wave/tile).
// Rotating 4-buffer schedule, 3 tiles in flight:
//   prologue: stage tiles 0,1,2 -> bufs 0,1,2 (12 loads out)
//   iter kt:  vmcnt(8)  [= tile kt's 4 loads landed; kt+1,kt+2 STAY IN FLIGHT]
//             s_barrier; stage tile kt+3 -> buf (kt+3)&3  [freed at kt-1, reads retired]
//             12 ds_read_b128 + 16 MFMA on buf kt&3
//   tail: vmcnt(4) / vmcnt(0). Never drains to 0 in the main loop (T4).
// Bounds: stage max byte = read max byte = 65536 = per-array size (exactly in-bounds).
__device__ __forceinline__ void gemm128_core(const ushort_t* __restrict__ Ag,   // + m0*2048
                                             const ushort_t* __restrict__ Bg,   // + n0*2048
                                             floatx4 (&acc)[2][4]) {
  __shared__ __align__(16) ushort_t As[4][128][64];
  __shared__ __align__(16) ushort_t Bs[4][128][64];
  int tid = threadIdx.x;             // 0..511
  int w = tid >> 6, lane = tid & 63; // 8 waves
  int wm = (w >> 1) * 32;            // 4 M-waves: rows [wm, wm+32)
  int wn = (w & 1) * 64;             // 2 N-waves: cols [wn, wn+64)
  int lr = lane & 15, quad = lane >> 4;
  int sx = lr & 7;
  char* Asb = (char*)As;
  char* Bsb = (char*)Bs;

  // staging: 2 issues per matrix; issue q covers rows q*64..q*64+63 (8 KB).
  // wave w: rows q*64 + w*8 + (lane>>3); chunk = lane&7, source pre-swizzled by row&7 (= lane>>3).
  size_t so0, so1;
  {
    int r0 = w * 8 + (lane >> 3);
    int r1 = 64 + w * 8 + (lane >> 3);
    int cs = ((lane & 7) ^ (lane >> 3)) * 16;
    so0 = (size_t)r0 * 4096 + cs;
    so1 = (size_t)r1 * 4096 + cs;
  }
  const char* abase = (const char*)Ag;
  const char* bbase = (const char*)Bg;

#define STAGE(b, kt)                                 \
  do {                                               \
    size_t ko = (size_t)(kt) * 128;                  \
    char* Ad = Asb + (b) * 16384 + w * 1024;         \
    char* Bd = Bsb + (b) * 16384 + w * 1024;         \
    ld_lds16(abase + so0 + ko, Ad);                  \
    ld_lds16(abase + so1 + ko, Ad + 8192);           \
    ld_lds16(bbase + so0 + ko, Bd);                  \
    ld_lds16(bbase + so1 + ko, Bd + 8192);           \
  } while (0)

#define COMPUTE(kt)                                                               \
  do {                                                                            \
    const char* Ab = Asb + ((kt) & 3) * 16384;                                    \
    const char* Bb = Bsb + ((kt) & 3) * 16384;                                    \
    short8 af[2][2], bfr[4][2];                                                   \
    _Pragma("unroll") for (int i = 0; i < 2; i++) {                               \
      size_t rb = (size_t)(wm + i * 16 + lr) * 128;                               \
      _Pragma("unroll") for (int ks = 0; ks < 2; ks++)                            \
        af[i][ks] = *(const short8*)(Ab + rb + (((ks * 4 + quad) ^ sx) << 4));    \
    }                                                                             \
    _Pragma("unroll") for (int j = 0; j < 4; j++) {                               \
      size_t rb = (size_t)(wn + j * 16 + lr) * 128;                               \
      _Pragma("unroll") for (int ks = 0; ks < 2; ks++)                            \
        bfr[j][ks] = *(const short8*)(Bb + rb + (((ks * 4 + quad) ^ sx) << 4));   \
    }                                                                             \
    _Pragma("unroll") for (int i = 0; i < 2; i++)                                 \
      _Pragma("unroll") for (int j = 0; j < 4; j++) {                             \
        acc[i][j] = __builtin_amdgcn_mfma_f32_16x16x32_bf16(af[i][0], bfr[j][0],  \
                                                            acc[i][j], 0, 0, 0); \
        acc[i][j] = __builtin_amdgcn_mfma_f32_16x16x32_bf16(af[i][1], bfr[j][1],  \
                                                            acc[i][j], 0, 0, 0); \
      }                                                                           \
  } while (0)

  // prologue: 3 tiles in flight
  STAGE(0, 0);
  STAGE(1, 1);
  STAGE(2, 2);

  for (int kt = 0; kt < 30; kt++) {
    asm volatile("s_waitcnt vmcnt(8)" ::: "memory");  // tile kt landed; kt+1,kt+2 in flight
    __builtin_amdgcn_s_barrier();
    __builtin_amdgcn_sched_barrier(0);
    if (kt < 29) STAGE((kt + 3) & 3, kt + 3);  // buf freed at kt-1 (reads retired pre-barrier)
    COMPUTE(kt);
  }
  asm volatile("s_waitcnt vmcnt(4)" ::: "memory");  // tile 30 landed
  __builtin_amdgcn_s_barrier();
  __builtin_amdgcn_sched_barrier(0);
  COMPUTE(30);
  asm volatile("s_waitcnt vmcnt(0)" ::: "memory");  // tile 31 landed
  __builtin_amdgcn_s_barrier();
  __builtin_amdgcn_sched_barrier(0);
  COMPUTE(31);
#undef STAGE
#undef COMPUTE
}

// ---------------- fused QKV GEMM: xb(M,2048)bf16 @ WT^T, N=3072, 128^2 tiles ----------------
__global__ __launch_bounds__(512) void gemm_qkv(const ushort_t* __restrict__ xb,
                                                const ushort_t* __restrict__ WT,
                                                ushort_t* __restrict__ qbf,
                                                float* __restrict__ outk,
                                                ushort_t* __restrict__ kbf,
                                                float* __restrict__ outv,
                                                const float* __restrict__ cosP,
                                                const float* __restrict__ sinP) {
  // bijective XCD swizzle: nwg = 768 = 8*96
  int o = blockIdx.y * 24 + blockIdx.x;
  int swz = (o & 7) * 96 + (o >> 3);
  int n0 = (swz % 24) * 128, m0 = (swz / 24) * 128;
  int tid = threadIdx.x;
  int w = tid >> 6, lane = tid & 63;
  int wm = (w >> 1) * 32, wn = (w & 1) * 64;
  int lr = lane & 15, quad = lane >> 4;

  floatx4 acc[2][4] = {};
  gemm128_core(xb + (size_t)m0 * 2048, WT + (size_t)n0 * 2048, acc);

  // epilogues (C frag: row=quad*4+r, col=lr); per-wave 32 rows x 64 cols
  if (n0 < 2048) {  // Q + rope -> qbf, pre-scaled by 0.125*log2e
    const float QS = 0.125f * 1.4426950408889634f;
#pragma unroll
    for (int i = 0; i < 2; i++)
#pragma unroll
      for (int j = 0; j < 2; j++) {
        int d = j * 16 + lr;
#pragma unroll
        for (int r = 0; r < 4; r++) {
          int row = m0 + wm + i * 16 + quad * 4 + r;
          int s = row & (S_ - 1);
          float c = cosP[s * 64 + d], sn = sinP[s * 64 + d];
          float x1 = acc[i][j][r], x2 = acc[i][j + 2][r];
          size_t oo = (size_t)row * 2048 + n0 + wn + d;
          qbf[oo] = f2bf((x1 * c - x2 * sn) * QS);
          qbf[oo + 32] = f2bf((x2 * c + x1 * sn) * QS);
        }
      }
  } else if (n0 < 2560) {  // K + rope -> outk fp32 (natural) + kbf bf16 (row-swizzled)
    int h = (n0 - 2048 + wn) >> 6;
#pragma unroll
    for (int i = 0; i < 2; i++)
#pragma unroll
      for (int j = 0; j < 2; j++) {
        int d = j * 16 + lr;
#pragma unroll
        for (int r = 0; r < 4; r++) {
          int row = m0 + wm + i * 16 + quad * 4 + r;
          int s = row & (S_ - 1), b = row >> 11;
          float c = cosP[s * 64 + d], sn = sinP[s * 64 + d];
          float x1 = acc[i][j][r], x2 = acc[i][j + 2][r];
          float y1 = x1 * c - x2 * sn, y2 = x2 * c + x1 * sn;
          size_t rowb = ((size_t)(b * NKV + h) * S_ + s) * 64;
          int xr = (s & 7) << 3;
          outk[rowb + d] = y1; outk[rowb + d + 32] = y2;
          kbf[rowb + (d ^ xr)] = f2bf(y1);
          kbf[rowb + ((d + 32) ^ xr)] = f2bf(y2);
        }
      }
  } else {  // V -> outv fp32
    int h = (n0 - 2560 + wn) >> 6;
#pragma unroll
    for (int i = 0; i < 2; i++)
#pragma unroll
      for (int j = 0; j < 4; j++) {
        int d = j * 16 + lr;
#pragma unroll
        for (int r = 0; r < 4; r++) {
          int row = m0 + wm + i * 16 + quad * 4 + r;
          int s = row & (S_ - 1), b = row >> 11;
          outv[((size_t)(b * NKV + h) * S_ + s) * 64 + d] = acc[i][j][r];
        }
      }
  }
}

// ---------------- O GEMM: ctx(qbf) @ WoT^T -> y fp32, 128^2 tiles ----------------
__global__ __launch_bounds__(512) void gemm_o(const ushort_t* __restrict__ ctx,
                                              const ushort_t* __restrict__ WoT,
                                              float* __restrict__ y) {
  // bijective XCD swizzle: nwg = 512 = 8*64
  int o = blockIdx.y * 16 + blockIdx.x;
  int swz = (o & 7) * 64 + (o >> 3);
  int n0 = (swz % 16) * 128, m0 = (swz / 16) * 128;
  int tid = threadIdx.x;
  int w = tid >> 6, lane = tid & 63;
  int wm = (w >> 1) * 32, wn = (w & 1) * 64;
  int lr = lane & 15, quad = lane >> 4;

  floatx4 acc[2][4] = {};
  gemm128_core(ctx + (size_t)m0 * 2048, WoT + (size_t)n0 * 2048, acc);

#pragma unroll
  for (int i = 0; i < 2; i++)
#pragma unroll
    for (int j = 0; j < 4; j++) {
      int row = m0 + wm + i * 16 + quad * 4;
      int col = n0 + wn + j * 16 + lr;
#pragma unroll
      for (int r = 0; r < 4; r++)
        y[(size_t)(row + r) * 2048 + col] = acc[i][j][r];
    }
}

// ---------------- MFMA flash attention: 2-phase async DMA pipeline (unchanged, verified) ----
__global__ __launch_bounds__(256, 4) void attn2(ushort_t* __restrict__ q,
                                                const ushort_t* __restrict__ k,
                                                const ushort_t* __restrict__ vt) {
  __shared__ __align__(16) ushort_t KV[2][2][64][64];  // [buf][K/V][row][col], swizzled content
  __shared__ __align__(16) ushort_t Ps[4][16][64];     // per-wave P^T, swizzled
  int bh = blockIdx.x;
  int qt = 31 - blockIdx.y;  // longest first
  int b = bh >> 5, h = bh & 31, g = h >> 2;
  int tid = threadIdx.x;
  int w = tid >> 6, lane = tid & 63;
  int lr = lane & 15, quad = lane >> 4;

  int qg = qt * 64 + w * 16 + lr;  // this lane's query row
  short8 aq0, aq1;                 // Q B-frag (Q^T operand), pre-scaled
  {
    const ushort_t* qp = q + ((size_t)(b * S_ + qg) * NH + h) * HD;
    aq0 = *(const short8*)(qp + quad * 8);
    aq1 = *(const short8*)(qp + 32 + quad * 8);
  }
  floatx4 od[4] = {};  // O^T[d=dn*16+quad*4+r][qrow=lr]
  float mi = -INFINITY, li = 0.f;

  const char* ksrc = (const char*)(k + (size_t)(b * NKV + g) * S_ * HD) + w * 2048 + lane * 16;
  const char* vsrc = (const char*)(vt + (size_t)(b * NKV + g) * S_ * HD) + w * 2048 + lane * 16;
  char* dB = (char*)&KV[0][0][0][0] + w * 2048;  // K region; +8192 = V region; +16384 = buf1

  int sw = (lr & 7) << 4;
  int ro0 = (quad * 16) ^ sw;
  int ro1 = (64 + quad * 16) ^ sw;
  char* Pw = (char*)&Ps[0][0][0] + w * 2048;

  // prologue: stage tile 0 -> buf 0
  ld_lds16(ksrc, dB);
  ld_lds16(ksrc + 1024, dB + 1024);
  ld_lds16(vsrc, dB + 8192);
  ld_lds16(vsrc + 1024, dB + 8192 + 1024);
  asm volatile("s_waitcnt vmcnt(0)" ::: "memory");
  __syncthreads();

  int cur = 0;
  for (int t = 0; t <= qt; t++) {
    if (t < qt) {
      const char* kn = ksrc + (size_t)(t + 1) * 8192;
      const char* vn = vsrc + (size_t)(t + 1) * 8192;
      char* d = dB + (cur ^ 1) * 16384;
      ld_lds16(kn, d); ld_lds16(kn + 1024, d + 1024);
      ld_lds16(vn, d + 8192); ld_lds16(vn + 1024, d + 8192 + 1024);
    }
    const char* Kb = (const char*)&KV[cur][0][0][0];
    const char* Vb = (const char*)&KV[cur][1][0][0];
    floatx4 sc[4];
#pragma unroll
    for (int kn = 0; kn < 4; kn++) {
      short8 a0 = *(const short8*)(Kb + (kn * 16 + lr) * 128 + ro0);
      short8 a1 = *(const short8*)(Kb + (kn * 16 + lr) * 128 + ro1);
      floatx4 c = {};
      c = __builtin_amdgcn_mfma_f32_16x16x32_bf16(a0, aq0, c, 0, 0, 0);
      c = __builtin_amdgcn_mfma_f32_16x16x32_bf16(a1, aq1, c, 0, 0, 0);
      sc[kn] = c;
    }
    float pv[16];
#pragma unroll
    for (int kn = 0; kn < 4; kn++)
#pragma unroll
      for (int r = 0; r < 4; r++) pv[kn * 4 + r] = sc[kn][r];
    if (t == qt) {  // causal mask: diagonal tile only
#pragma unroll
      for (int e = 0; e < 16; e++) {
        int kg = t * 64 + (e >> 2) * 16 + quad * 4 + (e & 3);
        if (kg > qg) pv[e] = -INFINITY;
      }
    }
    float mx = pv[0];
#pragma unroll
    for (int e = 1; e < 16; e++) mx = fmaxf(mx, pv[e]);
    mx = fmaxf(mx, __shfl_xor(mx, 16));
    mx = fmaxf(mx, __shfl_xor(mx, 32));
    if (__any(mx > mi + 11.5f)) {  // defer-max (T13)
      float mn = fmaxf(mi, mx);
      float al = fexp2(mi - mn);
      li *= al;
#pragma unroll
      for (int dn = 0; dn < 4; dn++) {
        od[dn][0] *= al; od[dn][1] *= al; od[dn][2] *= al; od[dn][3] *= al;
      }
      mi = mn;
    }
    float ps = 0.f;
#pragma unroll
    for (int e = 0; e < 16; e++) {
      pv[e] = fexp2(pv[e] - mi);
      ps += pv[e];
    }
    ps += __shfl_xor(ps, 16);
    ps += __shfl_xor(ps, 32);
    li += ps;
#pragma unroll
    for (int kn = 0; kn < 4; kn++) {
      unsigned int u0, u1;
      asm("v_cvt_pk_bf16_f32 %0, %1, %2" : "=v"(u0) : "v"(pv[kn * 4 + 0]), "v"(pv[kn * 4 + 1]));
      asm("v_cvt_pk_bf16_f32 %0, %1, %2" : "=v"(u1) : "v"(pv[kn * 4 + 2]), "v"(pv[kn * 4 + 3]));
      uint2 uu; uu.x = u0; uu.y = u1;
      *(uint2*)(Pw + lr * 128 + ((kn * 32 + quad * 8) ^ sw)) = uu;
    }
    short8 pb0 = *(const short8*)(Pw + lr * 128 + ro0);
    short8 pb1 = *(const short8*)(Pw + lr * 128 + ro1);
#pragma unroll
    for (int dn = 0; dn < 4; dn++) {
      short8 va = *(const short8*)(Vb + (dn * 16 + lr) * 128 + ro0);
      short8 vb = *(const short8*)(Vb + (dn * 16 + lr) * 128 + ro1);
      od[dn] = __builtin_amdgcn_mfma_f32_16x16x32_bf16(va, pb0, od[dn], 0, 0, 0);
      od[dn] = __builtin_amdgcn_mfma_f32_16x16x32_bf16(vb, pb1, od[dn], 0, 0, 0);
    }
    asm volatile("s_waitcnt vmcnt(0)" ::: "memory");
    __syncthreads();
    cur ^= 1;
  }
  float inv = 1.f / li;
  ushort_t* outp = q + ((size_t)(b * S_ + qg) * NH + h) * HD;
#pragma unroll
  for (int dn = 0; dn < 4; dn++) {
    short4v u;
    u[0] = (short)f2bf(od[dn][0] * inv); u[1] = (short)f2bf(od[dn][1] * inv);
    u[2] = (short)f2bf(od[dn][2] * inv); u[3] = (short)f2bf(od[dn][3] * inv);
    *(short4v*)(outp + dn * 16 + quad * 4) = u;
  }
}

extern "C" void kernel_launch(void* const* d_in, const int* in_sizes, int n_in,
                              void* d_out, int out_size, void* d_ws, size_t ws_size,
                              hipStream_t stream) {
  const float* x = (const float*)d_in[0];
  const float* cosT = (const float*)d_in[2];
  const float* sinT = (const float*)d_in[3];
  const float* Wq = (const float*)d_in[4];
  const float* Wk = (const float*)d_in[5];
  const float* Wv = (const float*)d_in[6];
  const float* Wo = (const float*)d_in[7];

  char* ws = (char*)d_ws;
  ushort_t* WT = (ushort_t*)(ws);                 // 12 MB (3072, 2048): Wq^T | Wk^T | Wv^T
  ushort_t* WoT = (ushort_t*)(ws + 12582912);     //  8 MB (2048, 2048)
  ushort_t* xb = (ushort_t*)(ws + 20971520);      // 16 MB (M, 2048) bf16
  ushort_t* qbf = (ushort_t*)(ws + 37748736);     // 16 MB (B,S,NH,HD); ctx in-place
  ushort_t* kbf = (ushort_t*)(ws + 54525952);     //  4 MB (B,NKV,S,HD) swizzled
  ushort_t* vt = (ushort_t*)(ws + 58720256);      //  4 MB tiled (bg,S/64,HD,64) swizzled

  float* y = (float*)d_out;                            // (B,S,E) fp32
  float* outk = y + (size_t)M_ * E_;                   // (B,NKV,S,HD) fp32
  float* outv = outk + (size_t)B_ * NKV * S_ * HD;     // (B,NKV,S,HD) fp32

  cast_x<<<dim3(4096), 256, 0, stream>>>(x, xb);
  transpose_w<<<dim3(64, 64), dim3(32, 8), 0, stream>>>(Wq, WT, 2048, 2048);
  transpose_w<<<dim3(16, 64), dim3(32, 8), 0, stream>>>(Wk, WT + 2048 * 2048, 2048, 512);
  transpose_w<<<dim3(16, 64), dim3(32, 8), 0, stream>>>(Wv, WT + 2560 * 2048, 2048, 512);
  transpose_w<<<dim3(64, 64), dim3(32, 8), 0, stream>>>(Wo, WoT, 2048, 2048);

  gemm_qkv<<<dim3(24, 32), 512, 0, stream>>>(xb, WT, qbf, outk, kbf, outv, cosT, sinT);
  transpose_v<<<dim3(32, 16), 256, 0, stream>>>(outv, vt);

  attn2<<<dim3(64, 32), 256, 0, stream>>>(qbf, kbf, vt);

  gemm_o<<<dim3(16, 32), 512, 0, stream>>>(qbf, WoT, y);
}

// Round 7
// 347.027 us; speedup vs baseline: 1.0502x; 1.0502x over previous
//
#include <hip/hip_runtime.h>
#include <hip/hip_bf16.h>
#include <math.h>

#define NH 32
#define NKV 8
#define HD 64
#define B_ 2
#define S_ 2048
#define E_ 2048
#define M_ 4096   // B_*S_

typedef unsigned short ushort_t;
typedef __attribute__((ext_vector_type(8))) short short8;
typedef __attribute__((ext_vector_type(4))) short short4v;
typedef __attribute__((ext_vector_type(4))) float floatx4;

__device__ inline unsigned short f2bf(float f) {
  unsigned int u = __float_as_uint(f);
  return (unsigned short)((u + 0x7FFFu + ((u >> 16) & 1u)) >> 16);  // RNE
}

__device__ inline float fexp2(float x) {  // raw v_exp_f32 (HW is base-2)
  float r;
  asm("v_exp_f32 %0, %1" : "=v"(r) : "v"(x));
  return r;
}

// async global->LDS, 16B per lane; lds base must be wave-uniform (HW adds lane*16)
__device__ inline void ld_lds16(const void* g, void* l) {
  __builtin_amdgcn_global_load_lds((__attribute__((address_space(1))) void*)g,
                                   (__attribute__((address_space(3))) void*)l, 16, 0, 0);
}

// ---------------- x fp32 -> bf16 ----------------
__global__ __launch_bounds__(256) void cast_x(const float* __restrict__ x,
                                              ushort_t* __restrict__ xb) {
  size_t i = ((size_t)blockIdx.x * 256 + threadIdx.x) * 8;
  float4 a = *(const float4*)(x + i);
  float4 b = *(const float4*)(x + i + 4);
  short8 o;
  o[0] = (short)f2bf(a.x); o[1] = (short)f2bf(a.y);
  o[2] = (short)f2bf(a.z); o[3] = (short)f2bf(a.w);
  o[4] = (short)f2bf(b.x); o[5] = (short)f2bf(b.y);
  o[6] = (short)f2bf(b.z); o[7] = (short)f2bf(b.w);
  *(short8*)(xb + i) = o;
}

// ---------------- transpose (R,C) fp32 -> (C,R) bf16 ----------------
__global__ __launch_bounds__(256) void transpose_w(const float* __restrict__ in,
                                                   ushort_t* __restrict__ out,
                                                   int R, int C) {
  __shared__ float tile[32][33];
  int c0 = blockIdx.x * 32, r0 = blockIdx.y * 32;
  int x = threadIdx.x, y0 = threadIdx.y;  // block (32,8)
  for (int i = 0; i < 4; i++) {
    int r = y0 + i * 8;
    tile[r][x] = in[(size_t)(r0 + r) * C + c0 + x];
  }
  __syncthreads();
  for (int i = 0; i < 4; i++) {
    int r = y0 + i * 8;
    out[(size_t)(c0 + r) * R + r0 + x] = f2bf(tile[x][r]);
  }
}

// ---------------- outv (B,NKV,S,HD) fp32 -> vt TILED (bg, S/64, HD, 64) bf16, swizzled ----
__global__ __launch_bounds__(256) void transpose_v(const float* __restrict__ outv,
                                                   ushort_t* __restrict__ vt) {
  __shared__ float t64[64][65];
  int bg = blockIdx.y;        // 0..15
  int tt = blockIdx.x;        // s-tile 0..31
  int s0 = tt * 64;
  int tid = threadIdx.x;
  size_t ibase = (size_t)bg * S_ * HD + (size_t)s0 * HD;
  for (int i = tid; i < 1024; i += 256) {
    int sr = i >> 4, dc = (i & 15) * 4;
    float4 v = *(const float4*)(outv + ibase + (size_t)sr * HD + dc);
    t64[sr][dc] = v.x; t64[sr][dc + 1] = v.y; t64[sr][dc + 2] = v.z; t64[sr][dc + 3] = v.w;
  }
  __syncthreads();
  size_t obase = ((size_t)bg * 32 + tt) * 4096;  // 64*64 elements per tile
  for (int i = tid; i < 512; i += 256) {
    int d = i >> 3, ss = (i & 7) * 8;
    short8 o;
#pragma unroll
    for (int e = 0; e < 8; e++) o[e] = (short)f2bf(t64[ss + e][d]);
    *(short8*)(vt + obase + d * 64 + (ss ^ ((d & 7) << 3))) = o;
  }
}

// ========== 128x128 / BK=64 GEMM core, T3 minimum 2-phase (round-5 verified, 563 TF) ==========
// 256 threads = 4 waves (2x2), per-wave C 64x64 = acc[4][4]. LDS 64 KiB (2 blocks/CU):
// double-buffered A[128][64] + B[128][64] bf16, XOR-swizzled 16B chunks, global_load_lds staged.
// Per K-tile: stage(kt+1 -> buf^1) || {16 ds_read_b128 + 32 MFMA on buf} -> __syncthreads.
__device__ __forceinline__ void gemm128_core(const ushort_t* __restrict__ Ag,   // + m0*2048
                                             const ushort_t* __restrict__ Bg,   // + n0*2048
                                             floatx4 (&acc)[4][4]) {
  __shared__ __align__(16) ushort_t As[2][128][64];
  __shared__ __align__(16) ushort_t Bs[2][128][64];
  int tid = threadIdx.x;
  int w = tid >> 6, lane = tid & 63;
  int wm = (w >> 1) * 64, wn = (w & 1) * 64;
  int lr = lane & 15, quad = lane >> 4;
  int sx = lr & 7;
  char* Asb = (char*)As;
  char* Bsb = (char*)Bs;

  size_t so[4];
#pragma unroll
  for (int s = 0; s < 4; s++)
    so[s] = (size_t)(w * 32 + s * 8 + (lane >> 3)) * 4096 + (size_t)(((lane & 7) ^ (lane >> 3)) * 16);
  const char* abase = (const char*)Ag;
  const char* bbase = (const char*)Bg;

#define STAGE128(buf, kt)                                          \
  do {                                                             \
    size_t ko = (size_t)(kt) * 128;                                \
    char* Ad = Asb + (buf) * 16384 + w * 4096;                     \
    char* Bd = Bsb + (buf) * 16384 + w * 4096;                     \
    _Pragma("unroll") for (int s = 0; s < 4; s++) {                \
      ld_lds16(abase + so[s] + ko, Ad + s * 1024);                 \
      ld_lds16(bbase + so[s] + ko, Bd + s * 1024);                 \
    }                                                              \
  } while (0)

  STAGE128(0, 0);
  __syncthreads();

  int cur = 0;
  for (int kt = 0; kt < 32; kt++) {
    if (kt < 31) STAGE128(cur ^ 1, kt + 1);  // issue BEFORE compute; lands by tile-end sync
    const char* Ab = Asb + cur * 16384;
    const char* Bb = Bsb + cur * 16384;
    short8 af[4][2], bfr[4][2];
#pragma unroll
    for (int i = 0; i < 4; i++) {
      size_t rb = (size_t)(wm + i * 16 + lr) * 128;
#pragma unroll
      for (int ks = 0; ks < 2; ks++)
        af[i][ks] = *(const short8*)(Ab + rb + (((ks * 4 + quad) ^ sx) << 4));
    }
#pragma unroll
    for (int j = 0; j < 4; j++) {
      size_t rb = (size_t)(wn + j * 16 + lr) * 128;
#pragma unroll
      for (int ks = 0; ks < 2; ks++)
        bfr[j][ks] = *(const short8*)(Bb + rb + (((ks * 4 + quad) ^ sx) << 4));
    }
#pragma unroll
    for (int i = 0; i < 4; i++)
#pragma unroll
      for (int j = 0; j < 4; j++) {
        acc[i][j] = __builtin_amdgcn_mfma_f32_16x16x32_bf16(af[i][0], bfr[j][0], acc[i][j], 0, 0, 0);
        acc[i][j] = __builtin_amdgcn_mfma_f32_16x16x32_bf16(af[i][1], bfr[j][1], acc[i][j], 0, 0, 0);
      }
    __syncthreads();  // vmcnt(0)+lgkmcnt(0)+barrier: kt+1 landed, all reads of cur done
    cur ^= 1;
  }
#undef STAGE128
}

// ---------------- fused QKV GEMM: xb(M,2048)bf16 @ WT^T, N=3072, 128^2 tiles ----------------
__global__ __launch_bounds__(256) void gemm_qkv(const ushort_t* __restrict__ xb,
                                                const ushort_t* __restrict__ WT,
                                                ushort_t* __restrict__ qbf,
                                                float* __restrict__ outk,
                                                ushort_t* __restrict__ kbf,
                                                float* __restrict__ outv,
                                                const float* __restrict__ cosP,
                                                const float* __restrict__ sinP) {
  // bijective XCD swizzle: nwg = 768 = 8*96
  int o = blockIdx.y * 24 + blockIdx.x;
  int swz = (o & 7) * 96 + (o >> 3);
  int n0 = (swz % 24) * 128, m0 = (swz / 24) * 128;
  int tid = threadIdx.x;
  int w = tid >> 6, lane = tid & 63;
  int wm = (w >> 1) * 64, wn = (w & 1) * 64;
  int lr = lane & 15, quad = lane >> 4;

  floatx4 acc[4][4] = {};
  gemm128_core(xb + (size_t)m0 * 2048, WT + (size_t)n0 * 2048, acc);

  // epilogues (C: row=quad*4+r, col=lr)
  if (n0 < 2048) {  // Q + rope -> qbf, pre-scaled by 0.125*log2e
    const float QS = 0.125f * 1.4426950408889634f;
#pragma unroll
    for (int i = 0; i < 4; i++)
#pragma unroll
      for (int j = 0; j < 2; j++) {
        int d = j * 16 + lr;
#pragma unroll
        for (int r = 0; r < 4; r++) {
          int row = m0 + wm + i * 16 + quad * 4 + r;
          int s = row & (S_ - 1);
          float c = cosP[s * 64 + d], sn = sinP[s * 64 + d];
          float x1 = acc[i][j][r], x2 = acc[i][j + 2][r];
          size_t oo = (size_t)row * 2048 + n0 + wn + d;
          qbf[oo] = f2bf((x1 * c - x2 * sn) * QS);
          qbf[oo + 32] = f2bf((x2 * c + x1 * sn) * QS);
        }
      }
  } else if (n0 < 2560) {  // K + rope -> outk fp32 (natural) + kbf bf16 (row-swizzled)
    int h = (n0 - 2048 + wn) >> 6;
#pragma unroll
    for (int i = 0; i < 4; i++)
#pragma unroll
      for (int j = 0; j < 2; j++) {
        int d = j * 16 + lr;
#pragma unroll
        for (int r = 0; r < 4; r++) {
          int row = m0 + wm + i * 16 + quad * 4 + r;
          int s = row & (S_ - 1), b = row >> 11;
          float c = cosP[s * 64 + d], sn = sinP[s * 64 + d];
          float x1 = acc[i][j][r], x2 = acc[i][j + 2][r];
          float y1 = x1 * c - x2 * sn, y2 = x2 * c + x1 * sn;
          size_t rowb = ((size_t)(b * NKV + h) * S_ + s) * 64;
          int xr = (s & 7) << 3;
          outk[rowb + d] = y1; outk[rowb + d + 32] = y2;
          kbf[rowb + (d ^ xr)] = f2bf(y1);
          kbf[rowb + ((d + 32) ^ xr)] = f2bf(y2);
        }
      }
  } else {  // V -> outv fp32
    int h = (n0 - 2560 + wn) >> 6;
#pragma unroll
    for (int i = 0; i < 4; i++)
#pragma unroll
      for (int j = 0; j < 4; j++) {
        int d = j * 16 + lr;
#pragma unroll
        for (int r = 0; r < 4; r++) {
          int row = m0 + wm + i * 16 + quad * 4 + r;
          int s = row & (S_ - 1), b = row >> 11;
          outv[((size_t)(b * NKV + h) * S_ + s) * 64 + d] = acc[i][j][r];
        }
      }
  }
}

// ---------------- O GEMM: ctx(qbf) @ WoT^T -> y fp32, 128^2 tiles ----------------
__global__ __launch_bounds__(256) void gemm_o(const ushort_t* __restrict__ ctx,
                                              const ushort_t* __restrict__ WoT,
                                              float* __restrict__ y) {
  // bijective XCD swizzle: nwg = 512 = 8*64
  int o = blockIdx.y * 16 + blockIdx.x;
  int swz = (o & 7) * 64 + (o >> 3);
  int n0 = (swz % 16) * 128, m0 = (swz / 16) * 128;
  int tid = threadIdx.x;
  int w = tid >> 6, lane = tid & 63;
  int wm = (w >> 1) * 64, wn = (w & 1) * 64;
  int lr = lane & 15, quad = lane >> 4;

  floatx4 acc[4][4] = {};
  gemm128_core(ctx + (size_t)m0 * 2048, WoT + (size_t)n0 * 2048, acc);

#pragma unroll
  for (int i = 0; i < 4; i++)
#pragma unroll
    for (int j = 0; j < 4; j++) {
      int row = m0 + wm + i * 16 + quad * 4;
      int col = n0 + wn + j * 16 + lr;
#pragma unroll
      for (int r = 0; r < 4; r++)
        y[(size_t)(row + r) * 2048 + col] = acc[i][j][r];
    }
}

// ---------------- MFMA flash attention v5: KVBLK=128, 2-phase DMA pipeline ----------------
// Two 64-key sub-tiles per iteration sharing ONE softmax pass: halves barriers/drains and
// cross-quad reductions, doubles MFMA per sync (32). LDS = KV 64KB + Ps 16KB = 80KB exactly
// -> 2 blocks/CU. Per-sub fragment/swizzle math identical to the round-5 verified kernel.
// setprio(1) around MFMA clusters (T5: attn blocks are phase-independent).
__global__ __launch_bounds__(256) void attn2(ushort_t* __restrict__ q,
                                             const ushort_t* __restrict__ k,
                                             const ushort_t* __restrict__ vt) {
  __shared__ __align__(16) ushort_t KV[2][2][2][64][64];  // [buf][sub][K/V][row][col], swizzled
  __shared__ __align__(16) ushort_t Ps[4][16][128];       // per-wave P^T (128 keys), swizzled
  int bh = blockIdx.x;
  int qt = 31 - blockIdx.y;  // longest first
  int b = bh >> 5, h = bh & 31, g = h >> 2;
  int tid = threadIdx.x;
  int w = tid >> 6, lane = tid & 63;
  int lr = lane & 15, quad = lane >> 4;

  int qg = qt * 64 + w * 16 + lr;  // this lane's query row
  short8 aq0, aq1;                 // Q B-frag (Q^T operand), pre-scaled 0.125*log2e
  {
    const ushort_t* qp = q + ((size_t)(b * S_ + qg) * NH + h) * HD;
    aq0 = *(const short8*)(qp + quad * 8);
    aq1 = *(const short8*)(qp + 32 + quad * 8);
  }
  floatx4 od[4] = {};  // O^T[d=dn*16+quad*4+r][qrow=lr]
  float mi = -INFINITY, li = 0.f;

  const char* kbase = (const char*)(k + (size_t)(b * NKV + g) * S_ * HD);
  const char* vbase = (const char*)(vt + (size_t)(b * NKV + g) * S_ * HD);
  char* KVb = (char*)&KV[0][0][0][0][0];
  int soff = w * 2048 + lane * 16;

  int sw = (lr & 7) << 4;
  int ro0 = (quad * 16) ^ sw;
  int ro1 = (64 + quad * 16) ^ sw;
  char* Pw = (char*)&Ps[0][0][0] + w * 4096;

  // stage one 128-key tile t: K 16KB (keys t*128..+127, row-swizzled) + V 16KB (vt tiles 2t,2t+1)
#define ASTAGE(buf, t)                                                                     \
  do {                                                                                     \
    _Pragma("unroll") for (int sub = 0; sub < 2; sub++) {                                  \
      const char* sk = kbase + (size_t)(t) * 16384 + sub * 8192 + soff;                    \
      const char* sv = vbase + ((size_t)(t) * 2 + sub) * 8192 + soff;                      \
      char* dk = KVb + (buf) * 32768 + sub * 16384 + w * 2048;                             \
      char* dv = dk + 8192;                                                                \
      ld_lds16(sk, dk); ld_lds16(sk + 1024, dk + 1024);                                    \
      ld_lds16(sv, dv); ld_lds16(sv + 1024, dv + 1024);                                    \
    }                                                                                      \
  } while (0)

  int nt = (qt + 2) >> 1;  // ceil((qt+1)*64 / 128)
  ASTAGE(0, 0);
  asm volatile("s_waitcnt vmcnt(0)" ::: "memory");
  __syncthreads();

  int cur = 0;
  for (int t = 0; t < nt; t++) {
    if (t + 1 < nt) ASTAGE(cur ^ 1, t + 1);  // lands by tile-end drain
    const char* Tb = KVb + cur * 32768;
    // S^T = K · Q^T : 8 key-frag-tiles (2 subs x 4), scores in log2 domain
    floatx4 sc[8];
    __builtin_amdgcn_s_setprio(1);
#pragma unroll
    for (int sub = 0; sub < 2; sub++) {
      const char* Kb = Tb + sub * 16384;
#pragma unroll
      for (int kn = 0; kn < 4; kn++) {
        short8 a0 = *(const short8*)(Kb + (kn * 16 + lr) * 128 + ro0);
        short8 a1 = *(const short8*)(Kb + (kn * 16 + lr) * 128 + ro1);
        floatx4 c = {};
        c = __builtin_amdgcn_mfma_f32_16x16x32_bf16(a0, aq0, c, 0, 0, 0);
        c = __builtin_amdgcn_mfma_f32_16x16x32_bf16(a1, aq1, c, 0, 0, 0);
        sc[sub * 4 + kn] = c;
      }
    }
    __builtin_amdgcn_s_setprio(0);
    // one softmax pass over 32 in-lane scores + cross-quad reduce
    float pv[32];
#pragma unroll
    for (int e = 0; e < 32; e++) pv[e] = sc[e >> 2][e & 3];
    if (t == nt - 1) {  // causal mask: last tile only (K/V data valid for all 2048 keys)
#pragma unroll
      for (int e = 0; e < 32; e++) {
        int kg = t * 128 + (e >> 4) * 64 + ((e >> 2) & 3) * 16 + quad * 4 + (e & 3);
        if (kg > qg) pv[e] = -INFINITY;
      }
    }
    float mx = pv[0];
#pragma unroll
    for (int e = 1; e < 32; e++) mx = fmaxf(mx, pv[e]);
    mx = fmaxf(mx, __shfl_xor(mx, 16));
    mx = fmaxf(mx, __shfl_xor(mx, 32));
    if (__any(mx > mi + 11.5f)) {  // defer-max (T13), log2 units
      float mn = fmaxf(mi, mx);
      float al = fexp2(mi - mn);
      li *= al;
#pragma unroll
      for (int dn = 0; dn < 4; dn++) {
        od[dn][0] *= al; od[dn][1] *= al; od[dn][2] *= al; od[dn][3] *= al;
      }
      mi = mn;
    }
    float ps = 0.f;
#pragma unroll
    for (int e = 0; e < 32; e++) {
      pv[e] = fexp2(pv[e] - mi);
      ps += pv[e];
    }
    ps += __shfl_xor(ps, 16);
    ps += __shfl_xor(ps, 32);
    li += ps;
    // P -> bf16 via v_cvt_pk, per-wave swizzled LDS (row lr, 256B rows, per-64-key-half swizzle)
#pragma unroll
    for (int sub = 0; sub < 2; sub++)
#pragma unroll
      for (int kn = 0; kn < 4; kn++) {
        int e = sub * 16 + kn * 4;
        unsigned int u0, u1;
        asm("v_cvt_pk_bf16_f32 %0, %1, %2" : "=v"(u0) : "v"(pv[e + 0]), "v"(pv[e + 1]));
        asm("v_cvt_pk_bf16_f32 %0, %1, %2" : "=v"(u1) : "v"(pv[e + 2]), "v"(pv[e + 3]));
        uint2 uu; uu.x = u0; uu.y = u1;
        *(uint2*)(Pw + lr * 256 + sub * 128 + ((kn * 32 + quad * 8) ^ sw)) = uu;
      }
    // O^T += V^T · P^T over 128 keys (2 subs)
    __builtin_amdgcn_s_setprio(1);
#pragma unroll
    for (int sub = 0; sub < 2; sub++) {
      short8 pb0 = *(const short8*)(Pw + lr * 256 + sub * 128 + ro0);
      short8 pb1 = *(const short8*)(Pw + lr * 256 + sub * 128 + ro1);
      const char* Vb = Tb + sub * 16384 + 8192;
#pragma unroll
      for (int dn = 0; dn < 4; dn++) {
        short8 va = *(const short8*)(Vb + (dn * 16 + lr) * 128 + ro0);
        short8 vb = *(const short8*)(Vb + (dn * 16 + lr) * 128 + ro1);
        od[dn] = __builtin_amdgcn_mfma_f32_16x16x32_bf16(va, pb0, od[dn], 0, 0, 0);
        od[dn] = __builtin_amdgcn_mfma_f32_16x16x32_bf16(vb, pb1, od[dn], 0, 0, 0);
      }
    }
    __builtin_amdgcn_s_setprio(0);
    // next tile's DMA landed; all waves done reading cur before overwrite
    asm volatile("s_waitcnt vmcnt(0)" ::: "memory");
    __syncthreads();
    cur ^= 1;
  }
#undef ASTAGE
  float inv = 1.f / li;
  ushort_t* outp = q + ((size_t)(b * S_ + qg) * NH + h) * HD;
#pragma unroll
  for (int dn = 0; dn < 4; dn++) {
    short4v u;
    u[0] = (short)f2bf(od[dn][0] * inv); u[1] = (short)f2bf(od[dn][1] * inv);
    u[2] = (short)f2bf(od[dn][2] * inv); u[3] = (short)f2bf(od[dn][3] * inv);
    *(short4v*)(outp + dn * 16 + quad * 4) = u;
  }
}

extern "C" void kernel_launch(void* const* d_in, const int* in_sizes, int n_in,
                              void* d_out, int out_size, void* d_ws, size_t ws_size,
                              hipStream_t stream) {
  const float* x = (const float*)d_in[0];
  const float* cosT = (const float*)d_in[2];
  const float* sinT = (const float*)d_in[3];
  const float* Wq = (const float*)d_in[4];
  const float* Wk = (const float*)d_in[5];
  const float* Wv = (const float*)d_in[6];
  const float* Wo = (const float*)d_in[7];

  char* ws = (char*)d_ws;
  ushort_t* WT = (ushort_t*)(ws);                 // 12 MB (3072, 2048): Wq^T | Wk^T | Wv^T
  ushort_t* WoT = (ushort_t*)(ws + 12582912);     //  8 MB (2048, 2048)
  ushort_t* xb = (ushort_t*)(ws + 20971520);      // 16 MB (M, 2048) bf16
  ushort_t* qbf = (ushort_t*)(ws + 37748736);     // 16 MB (B,S,NH,HD); ctx in-place
  ushort_t* kbf = (ushort_t*)(ws + 54525952);     //  4 MB (B,NKV,S,HD) swizzled
  ushort_t* vt = (ushort_t*)(ws + 58720256);      //  4 MB tiled (bg,S/64,HD,64) swizzled

  float* y = (float*)d_out;                            // (B,S,E) fp32
  float* outk = y + (size_t)M_ * E_;                   // (B,NKV,S,HD) fp32
  float* outv = outk + (size_t)B_ * NKV * S_ * HD;     // (B,NKV,S,HD) fp32

  cast_x<<<dim3(4096), 256, 0, stream>>>(x, xb);
  transpose_w<<<dim3(64, 64), dim3(32, 8), 0, stream>>>(Wq, WT, 2048, 2048);
  transpose_w<<<dim3(16, 64), dim3(32, 8), 0, stream>>>(Wk, WT + 2048 * 2048, 2048, 512);
  transpose_w<<<dim3(16, 64), dim3(32, 8), 0, stream>>>(Wv, WT + 2560 * 2048, 2048, 512);
  transpose_w<<<dim3(64, 64), dim3(32, 8), 0, stream>>>(Wo, WoT, 2048, 2048);

  gemm_qkv<<<dim3(24, 32), 256, 0, stream>>>(xb, WT, qbf, outk, kbf, outv, cosT, sinT);
  transpose_v<<<dim3(32, 16), 256, 0, stream>>>(outv, vt);

  attn2<<<dim3(64, 32), 256, 0, stream>>>(qbf, kbf, vt);

  gemm_o<<<dim3(16, 32), 256, 0, stream>>>(qbf, WoT, y);
}

// Round 8
// 322.199 us; speedup vs baseline: 1.1311x; 1.0771x over previous
//
#include <hip/hip_runtime.h>
#include <hip/hip_bf16.h>
#include <math.h>

#define NH 32
#define NKV 8
#define HD 64
#define B_ 2
#define S_ 2048
#define E_ 2048
#define M_ 4096   // B_*S_

typedef unsigned short ushort_t;
typedef __attribute__((ext_vector_type(8))) short short8;
typedef __attribute__((ext_vector_type(4))) short short4v;
typedef __attribute__((ext_vector_type(4))) float floatx4;

__device__ inline unsigned short f2bf(float f) {
  unsigned int u = __float_as_uint(f);
  return (unsigned short)((u + 0x7FFFu + ((u >> 16) & 1u)) >> 16);  // RNE
}

__device__ inline float fexp2(float x) {  // raw v_exp_f32 (HW is base-2)
  float r;
  asm("v_exp_f32 %0, %1" : "=v"(r) : "v"(x));
  return r;
}

// async global->LDS, 16B per lane; lds base must be wave-uniform (HW adds lane*16)
__device__ inline void ld_lds16(const void* g, void* l) {
  __builtin_amdgcn_global_load_lds((__attribute__((address_space(1))) void*)g,
                                   (__attribute__((address_space(3))) void*)l, 16, 0, 0);
}

// ---------------- fused prep: x cast + 4 weight transposes in ONE launch ----------------
// blocks [0,4096): cast_x ; [4096,8192): Wq^T ; [8192,9216): Wk^T ; [9216,10240): Wv^T ;
// [10240,14336): Wo^T. Branches are block-uniform. Replaces 5 serialized small launches.
__device__ inline void transp32(const float* __restrict__ in, ushort_t* __restrict__ out,
                                int R, int C, int bx, int by, int tid, float (*tile)[33]) {
  int c0 = bx * 32, r0 = by * 32;
  int x = tid & 31, y0 = tid >> 5;  // (32,8)
  for (int i = 0; i < 4; i++) {
    int r = y0 + i * 8;
    tile[r][x] = in[(size_t)(r0 + r) * C + c0 + x];
  }
  __syncthreads();
  for (int i = 0; i < 4; i++) {
    int r = y0 + i * 8;
    out[(size_t)(c0 + r) * R + r0 + x] = f2bf(tile[x][r]);
  }
}

__global__ __launch_bounds__(256) void prep(const float* __restrict__ x,
                                            ushort_t* __restrict__ xb,
                                            const float* __restrict__ Wq,
                                            const float* __restrict__ Wk,
                                            const float* __restrict__ Wv,
                                            const float* __restrict__ Wo,
                                            ushort_t* __restrict__ WT,
                                            ushort_t* __restrict__ WoT) {
  __shared__ float tile[32][33];
  int bid = blockIdx.x, tid = threadIdx.x;
  if (bid < 4096) {  // cast x fp32 -> bf16 (8 elems/thread)
    size_t i = ((size_t)bid * 256 + tid) * 8;
    float4 a = *(const float4*)(x + i);
    float4 b = *(const float4*)(x + i + 4);
    short8 o;
    o[0] = (short)f2bf(a.x); o[1] = (short)f2bf(a.y);
    o[2] = (short)f2bf(a.z); o[3] = (short)f2bf(a.w);
    o[4] = (short)f2bf(b.x); o[5] = (short)f2bf(b.y);
    o[6] = (short)f2bf(b.z); o[7] = (short)f2bf(b.w);
    *(short8*)(xb + i) = o;
    return;
  }
  bid -= 4096;
  if (bid < 4096) { transp32(Wq, WT, 2048, 2048, bid & 63, bid >> 6, tid, tile); return; }
  bid -= 4096;
  if (bid < 1024) { transp32(Wk, WT + 2048 * 2048, 2048, 512, bid & 15, bid >> 4, tid, tile); return; }
  bid -= 1024;
  if (bid < 1024) { transp32(Wv, WT + 2560 * 2048, 2048, 512, bid & 15, bid >> 4, tid, tile); return; }
  bid -= 1024;
  transp32(Wo, WoT, 2048, 2048, bid & 63, bid >> 6, tid, tile);
}

// ---------------- outv (B,NKV,S,HD) fp32 -> vt TILED (bg, S/64, HD, 64) bf16, swizzled ----
__global__ __launch_bounds__(256) void transpose_v(const float* __restrict__ outv,
                                                   ushort_t* __restrict__ vt) {
  __shared__ float t64[64][65];
  int bg = blockIdx.y;        // 0..15
  int tt = blockIdx.x;        // s-tile 0..31
  int s0 = tt * 64;
  int tid = threadIdx.x;
  size_t ibase = (size_t)bg * S_ * HD + (size_t)s0 * HD;
  for (int i = tid; i < 1024; i += 256) {
    int sr = i >> 4, dc = (i & 15) * 4;
    float4 v = *(const float4*)(outv + ibase + (size_t)sr * HD + dc);
    t64[sr][dc] = v.x; t64[sr][dc + 1] = v.y; t64[sr][dc + 2] = v.z; t64[sr][dc + 3] = v.w;
  }
  __syncthreads();
  size_t obase = ((size_t)bg * 32 + tt) * 4096;  // 64*64 elements per tile
  for (int i = tid; i < 512; i += 256) {
    int d = i >> 3, ss = (i & 7) * 8;
    short8 o;
#pragma unroll
    for (int e = 0; e < 8; e++) o[e] = (short)f2bf(t64[ss + e][d]);
    *(short8*)(vt + obase + d * 64 + (ss ^ ((d & 7) << 3))) = o;
  }
}

// ========== 128x128 / BK=64 GEMM core, T3 minimum 2-phase (round-5 verified, 563 TF) ==========
// 256 threads = 4 waves (2x2), per-wave C 64x64 = acc[4][4]. LDS 64 KiB (2 blocks/CU):
// double-buffered A[128][64] + B[128][64] bf16, XOR-swizzled 16B chunks, global_load_lds staged.
// Per K-tile: stage(kt+1 -> buf^1) || {16 ds_read_b128 + 32 MFMA on buf} -> __syncthreads.
__device__ __forceinline__ void gemm128_core(const ushort_t* __restrict__ Ag,   // + m0*2048
                                             const ushort_t* __restrict__ Bg,   // + n0*2048
                                             floatx4 (&acc)[4][4]) {
  __shared__ __align__(16) ushort_t As[2][128][64];
  __shared__ __align__(16) ushort_t Bs[2][128][64];
  int tid = threadIdx.x;
  int w = tid >> 6, lane = tid & 63;
  int wm = (w >> 1) * 64, wn = (w & 1) * 64;
  int lr = lane & 15, quad = lane >> 4;
  int sx = lr & 7;
  char* Asb = (char*)As;
  char* Bsb = (char*)Bs;

  size_t so[4];
#pragma unroll
  for (int s = 0; s < 4; s++)
    so[s] = (size_t)(w * 32 + s * 8 + (lane >> 3)) * 4096 + (size_t)(((lane & 7) ^ (lane >> 3)) * 16);
  const char* abase = (const char*)Ag;
  const char* bbase = (const char*)Bg;

#define STAGE128(buf, kt)                                          \
  do {                                                             \
    size_t ko = (size_t)(kt) * 128;                                \
    char* Ad = Asb + (buf) * 16384 + w * 4096;                     \
    char* Bd = Bsb + (buf) * 16384 + w * 4096;                     \
    _Pragma("unroll") for (int s = 0; s < 4; s++) {                \
      ld_lds16(abase + so[s] + ko, Ad + s * 1024);                 \
      ld_lds16(bbase + so[s] + ko, Bd + s * 1024);                 \
    }                                                              \
  } while (0)

  STAGE128(0, 0);
  __syncthreads();

  int cur = 0;
  for (int kt = 0; kt < 32; kt++) {
    if (kt < 31) STAGE128(cur ^ 1, kt + 1);  // issue BEFORE compute; lands by tile-end sync
    const char* Ab = Asb + cur * 16384;
    const char* Bb = Bsb + cur * 16384;
    short8 af[4][2], bfr[4][2];
#pragma unroll
    for (int i = 0; i < 4; i++) {
      size_t rb = (size_t)(wm + i * 16 + lr) * 128;
#pragma unroll
      for (int ks = 0; ks < 2; ks++)
        af[i][ks] = *(const short8*)(Ab + rb + (((ks * 4 + quad) ^ sx) << 4));
    }
#pragma unroll
    for (int j = 0; j < 4; j++) {
      size_t rb = (size_t)(wn + j * 16 + lr) * 128;
#pragma unroll
      for (int ks = 0; ks < 2; ks++)
        bfr[j][ks] = *(const short8*)(Bb + rb + (((ks * 4 + quad) ^ sx) << 4));
    }
#pragma unroll
    for (int i = 0; i < 4; i++)
#pragma unroll
      for (int j = 0; j < 4; j++) {
        acc[i][j] = __builtin_amdgcn_mfma_f32_16x16x32_bf16(af[i][0], bfr[j][0], acc[i][j], 0, 0, 0);
        acc[i][j] = __builtin_amdgcn_mfma_f32_16x16x32_bf16(af[i][1], bfr[j][1], acc[i][j], 0, 0, 0);
      }
    __syncthreads();  // vmcnt(0)+lgkmcnt(0)+barrier: kt+1 landed, all reads of cur done
    cur ^= 1;
  }
#undef STAGE128
}

// ---------------- fused QKV GEMM: xb(M,2048)bf16 @ WT^T, N=3072, 128^2 tiles ----------------
__global__ __launch_bounds__(256) void gemm_qkv(const ushort_t* __restrict__ xb,
                                                const ushort_t* __restrict__ WT,
                                                ushort_t* __restrict__ qbf,
                                                float* __restrict__ outk,
                                                ushort_t* __restrict__ kbf,
                                                float* __restrict__ outv,
                                                const float* __restrict__ cosP,
                                                const float* __restrict__ sinP) {
  // rectangular XCD partition: each XCD owns an 8m x 12n tile rectangle (10 MB L2 footprint)
  int o = blockIdx.y * 24 + blockIdx.x;   // nwg = 768 = 8 * 96
  int xcd = o & 7, i = o >> 3;            // i in [0,96)
  int mg = xcd >> 1, ng = xcd & 1;        // 4 m-groups x 2 n-groups
  int m0 = (mg * 8 + i / 12) * 128;
  int n0 = (ng * 12 + i % 12) * 128;
  int tid = threadIdx.x;
  int w = tid >> 6, lane = tid & 63;
  int wm = (w >> 1) * 64, wn = (w & 1) * 64;
  int lr = lane & 15, quad = lane >> 4;

  floatx4 acc[4][4] = {};
  gemm128_core(xb + (size_t)m0 * 2048, WT + (size_t)n0 * 2048, acc);

  // epilogues (C: row=quad*4+r, col=lr)
  if (n0 < 2048) {  // Q + rope -> qbf, pre-scaled by 0.125*log2e
    const float QS = 0.125f * 1.4426950408889634f;
#pragma unroll
    for (int i2 = 0; i2 < 4; i2++)
#pragma unroll
      for (int j = 0; j < 2; j++) {
        int d = j * 16 + lr;
#pragma unroll
        for (int r = 0; r < 4; r++) {
          int row = m0 + wm + i2 * 16 + quad * 4 + r;
          int s = row & (S_ - 1);
          float c = cosP[s * 64 + d], sn = sinP[s * 64 + d];
          float x1 = acc[i2][j][r], x2 = acc[i2][j + 2][r];
          size_t oo = (size_t)row * 2048 + n0 + wn + d;
          qbf[oo] = f2bf((x1 * c - x2 * sn) * QS);
          qbf[oo + 32] = f2bf((x2 * c + x1 * sn) * QS);
        }
      }
  } else if (n0 < 2560) {  // K + rope -> outk fp32 (natural) + kbf bf16 (row-swizzled)
    int h = (n0 - 2048 + wn) >> 6;
#pragma unroll
    for (int i2 = 0; i2 < 4; i2++)
#pragma unroll
      for (int j = 0; j < 2; j++) {
        int d = j * 16 + lr;
#pragma unroll
        for (int r = 0; r < 4; r++) {
          int row = m0 + wm + i2 * 16 + quad * 4 + r;
          int s = row & (S_ - 1), b = row >> 11;
          float c = cosP[s * 64 + d], sn = sinP[s * 64 + d];
          float x1 = acc[i2][j][r], x2 = acc[i2][j + 2][r];
          float y1 = x1 * c - x2 * sn, y2 = x2 * c + x1 * sn;
          size_t rowb = ((size_t)(b * NKV + h) * S_ + s) * 64;
          int xr = (s & 7) << 3;
          outk[rowb + d] = y1; outk[rowb + d + 32] = y2;
          kbf[rowb + (d ^ xr)] = f2bf(y1);
          kbf[rowb + ((d + 32) ^ xr)] = f2bf(y2);
        }
      }
  } else {  // V -> outv fp32
    int h = (n0 - 2560 + wn) >> 6;
#pragma unroll
    for (int i2 = 0; i2 < 4; i2++)
#pragma unroll
      for (int j = 0; j < 4; j++) {
        int d = j * 16 + lr;
#pragma unroll
        for (int r = 0; r < 4; r++) {
          int row = m0 + wm + i2 * 16 + quad * 4 + r;
          int s = row & (S_ - 1), b = row >> 11;
          outv[((size_t)(b * NKV + h) * S_ + s) * 64 + d] = acc[i2][j][r];
        }
      }
  }
}

// ---------------- O GEMM: ctx(qbf) @ WoT^T -> y fp32, 128^2 tiles ----------------
__global__ __launch_bounds__(256) void gemm_o(const ushort_t* __restrict__ ctx,
                                              const ushort_t* __restrict__ WoT,
                                              float* __restrict__ y) {
  // rectangular XCD partition: each XCD owns an 8m x 8n rectangle (8 MB L2 footprint)
  int o = blockIdx.y * 16 + blockIdx.x;   // nwg = 512 = 8 * 64
  int xcd = o & 7, i = o >> 3;            // i in [0,64)
  int mg = xcd >> 1, ng = xcd & 1;
  int m0 = (mg * 8 + (i >> 3)) * 128;
  int n0 = (ng * 8 + (i & 7)) * 128;
  int tid = threadIdx.x;
  int w = tid >> 6, lane = tid & 63;
  int wm = (w >> 1) * 64, wn = (w & 1) * 64;
  int lr = lane & 15, quad = lane >> 4;

  floatx4 acc[4][4] = {};
  gemm128_core(ctx + (size_t)m0 * 2048, WoT + (size_t)n0 * 2048, acc);

#pragma unroll
  for (int i2 = 0; i2 < 4; i2++)
#pragma unroll
    for (int j = 0; j < 4; j++) {
      int row = m0 + wm + i2 * 16 + quad * 4;
      int col = n0 + wn + j * 16 + lr;
#pragma unroll
      for (int r = 0; r < 4; r++)
        y[(size_t)(row + r) * 2048 + col] = acc[i2][j][r];
    }
}

// ---------------- MFMA flash attention: round-5 2-phase DMA pipeline + setprio (T5) ----------
__global__ __launch_bounds__(256, 4) void attn2(ushort_t* __restrict__ q,
                                                const ushort_t* __restrict__ k,
                                                const ushort_t* __restrict__ vt) {
  __shared__ __align__(16) ushort_t KV[2][2][64][64];  // [buf][K/V][row][col], swizzled content
  __shared__ __align__(16) ushort_t Ps[4][16][64];     // per-wave P^T, swizzled
  int bh = blockIdx.x;
  int qt = 31 - blockIdx.y;  // longest first
  int b = bh >> 5, h = bh & 31, g = h >> 2;
  int tid = threadIdx.x;
  int w = tid >> 6, lane = tid & 63;
  int lr = lane & 15, quad = lane >> 4;

  int qg = qt * 64 + w * 16 + lr;  // this lane's query row
  short8 aq0, aq1;                 // Q B-frag (Q^T operand), pre-scaled 0.125*log2e
  {
    const ushort_t* qp = q + ((size_t)(b * S_ + qg) * NH + h) * HD;
    aq0 = *(const short8*)(qp + quad * 8);
    aq1 = *(const short8*)(qp + 32 + quad * 8);
  }
  floatx4 od[4] = {};  // O^T[d=dn*16+quad*4+r][qrow=lr]
  float mi = -INFINITY, li = 0.f;

  const char* ksrc = (const char*)(k + (size_t)(b * NKV + g) * S_ * HD) + w * 2048 + lane * 16;
  const char* vsrc = (const char*)(vt + (size_t)(b * NKV + g) * S_ * HD) + w * 2048 + lane * 16;
  char* dB = (char*)&KV[0][0][0][0] + w * 2048;  // K region; +8192 = V region; +16384 = buf1

  int sw = (lr & 7) << 4;
  int ro0 = (quad * 16) ^ sw;
  int ro1 = (64 + quad * 16) ^ sw;
  char* Pw = (char*)&Ps[0][0][0] + w * 2048;

  // prologue: stage tile 0 -> buf 0
  ld_lds16(ksrc, dB);
  ld_lds16(ksrc + 1024, dB + 1024);
  ld_lds16(vsrc, dB + 8192);
  ld_lds16(vsrc + 1024, dB + 8192 + 1024);
  asm volatile("s_waitcnt vmcnt(0)" ::: "memory");
  __syncthreads();

  int cur = 0;
  for (int t = 0; t <= qt; t++) {
    if (t < qt) {
      const char* kn = ksrc + (size_t)(t + 1) * 8192;
      const char* vn = vsrc + (size_t)(t + 1) * 8192;
      char* d = dB + (cur ^ 1) * 16384;
      ld_lds16(kn, d); ld_lds16(kn + 1024, d + 1024);
      ld_lds16(vn, d + 8192); ld_lds16(vn + 1024, d + 8192 + 1024);
    }
    const char* Kb = (const char*)&KV[cur][0][0][0];
    const char* Vb = (const char*)&KV[cur][1][0][0];
    floatx4 sc[4];
    __builtin_amdgcn_s_setprio(1);
#pragma unroll
    for (int kn = 0; kn < 4; kn++) {
      short8 a0 = *(const short8*)(Kb + (kn * 16 + lr) * 128 + ro0);
      short8 a1 = *(const short8*)(Kb + (kn * 16 + lr) * 128 + ro1);
      floatx4 c = {};
      c = __builtin_amdgcn_mfma_f32_16x16x32_bf16(a0, aq0, c, 0, 0, 0);
      c = __builtin_amdgcn_mfma_f32_16x16x32_bf16(a1, aq1, c, 0, 0, 0);
      sc[kn] = c;
    }
    __builtin_amdgcn_s_setprio(0);
    float pv[16];
#pragma unroll
    for (int kn = 0; kn < 4; kn++)
#pragma unroll
      for (int r = 0; r < 4; r++) pv[kn * 4 + r] = sc[kn][r];
    if (t == qt) {  // causal mask: diagonal tile only
#pragma unroll
      for (int e = 0; e < 16; e++) {
        int kg = t * 64 + (e >> 2) * 16 + quad * 4 + (e & 3);
        if (kg > qg) pv[e] = -INFINITY;
      }
    }
    float mx = pv[0];
#pragma unroll
    for (int e = 1; e < 16; e++) mx = fmaxf(mx, pv[e]);
    mx = fmaxf(mx, __shfl_xor(mx, 16));
    mx = fmaxf(mx, __shfl_xor(mx, 32));
    if (__any(mx > mi + 11.5f)) {  // defer-max (T13), log2 units
      float mn = fmaxf(mi, mx);
      float al = fexp2(mi - mn);
      li *= al;
#pragma unroll
      for (int dn = 0; dn < 4; dn++) {
        od[dn][0] *= al; od[dn][1] *= al; od[dn][2] *= al; od[dn][3] *= al;
      }
      mi = mn;
    }
    float ps = 0.f;
#pragma unroll
    for (int e = 0; e < 16; e++) {
      pv[e] = fexp2(pv[e] - mi);
      ps += pv[e];
    }
    ps += __shfl_xor(ps, 16);
    ps += __shfl_xor(ps, 32);
    li += ps;
#pragma unroll
    for (int kn = 0; kn < 4; kn++) {
      unsigned int u0, u1;
      asm("v_cvt_pk_bf16_f32 %0, %1, %2" : "=v"(u0) : "v"(pv[kn * 4 + 0]), "v"(pv[kn * 4 + 1]));
      asm("v_cvt_pk_bf16_f32 %0, %1, %2" : "=v"(u1) : "v"(pv[kn * 4 + 2]), "v"(pv[kn * 4 + 3]));
      uint2 uu; uu.x = u0; uu.y = u1;
      *(uint2*)(Pw + lr * 128 + ((kn * 32 + quad * 8) ^ sw)) = uu;
    }
    short8 pb0 = *(const short8*)(Pw + lr * 128 + ro0);
    short8 pb1 = *(const short8*)(Pw + lr * 128 + ro1);
    __builtin_amdgcn_s_setprio(1);
#pragma unroll
    for (int dn = 0; dn < 4; dn++) {
      short8 va = *(const short8*)(Vb + (dn * 16 + lr) * 128 + ro0);
      short8 vb = *(const short8*)(Vb + (dn * 16 + lr) * 128 + ro1);
      od[dn] = __builtin_amdgcn_mfma_f32_16x16x32_bf16(va, pb0, od[dn], 0, 0, 0);
      od[dn] = __builtin_amdgcn_mfma_f32_16x16x32_bf16(vb, pb1, od[dn], 0, 0, 0);
    }
    __builtin_amdgcn_s_setprio(0);
    asm volatile("s_waitcnt vmcnt(0)" ::: "memory");
    __syncthreads();
    cur ^= 1;
  }
  float inv = 1.f / li;
  ushort_t* outp = q + ((size_t)(b * S_ + qg) * NH + h) * HD;
#pragma unroll
  for (int dn = 0; dn < 4; dn++) {
    short4v u;
    u[0] = (short)f2bf(od[dn][0] * inv); u[1] = (short)f2bf(od[dn][1] * inv);
    u[2] = (short)f2bf(od[dn][2] * inv); u[3] = (short)f2bf(od[dn][3] * inv);
    *(short4v*)(outp + dn * 16 + quad * 4) = u;
  }
}

extern "C" void kernel_launch(void* const* d_in, const int* in_sizes, int n_in,
                              void* d_out, int out_size, void* d_ws, size_t ws_size,
                              hipStream_t stream) {
  const float* x = (const float*)d_in[0];
  const float* cosT = (const float*)d_in[2];
  const float* sinT = (const float*)d_in[3];
  const float* Wq = (const float*)d_in[4];
  const float* Wk = (const float*)d_in[5];
  const float* Wv = (const float*)d_in[6];
  const float* Wo = (const float*)d_in[7];

  char* ws = (char*)d_ws;
  ushort_t* WT = (ushort_t*)(ws);                 // 12 MB (3072, 2048): Wq^T | Wk^T | Wv^T
  ushort_t* WoT = (ushort_t*)(ws + 12582912);     //  8 MB (2048, 2048)
  ushort_t* xb = (ushort_t*)(ws + 20971520);      // 16 MB (M, 2048) bf16
  ushort_t* qbf = (ushort_t*)(ws + 37748736);     // 16 MB (B,S,NH,HD); ctx in-place
  ushort_t* kbf = (ushort_t*)(ws + 54525952);     //  4 MB (B,NKV,S,HD) swizzled
  ushort_t* vt = (ushort_t*)(ws + 58720256);      //  4 MB tiled (bg,S/64,HD,64) swizzled

  float* y = (float*)d_out;                            // (B,S,E) fp32
  float* outk = y + (size_t)M_ * E_;                   // (B,NKV,S,HD) fp32
  float* outv = outk + (size_t)B_ * NKV * S_ * HD;     // (B,NKV,S,HD) fp32

  prep<<<dim3(14336), 256, 0, stream>>>(x, xb, Wq, Wk, Wv, Wo, WT, WoT);

  gemm_qkv<<<dim3(24, 32), 256, 0, stream>>>(xb, WT, qbf, outk, kbf, outv, cosT, sinT);
  transpose_v<<<dim3(32, 16), 256, 0, stream>>>(outv, vt);

  attn2<<<dim3(64, 32), 256, 0, stream>>>(qbf, kbf, vt);

  gemm_o<<<dim3(16, 32), 256, 0, stream>>>(qbf, WoT, y);
}

// Round 9
// 308.581 us; speedup vs baseline: 1.1811x; 1.0441x over previous
//
#include <hip/hip_runtime.h>
#include <hip/hip_bf16.h>
#include <math.h>

#define NH 32
#define NKV 8
#define HD 64
#define B_ 2
#define S_ 2048
#define E_ 2048
#define M_ 4096   // B_*S_

typedef unsigned short ushort_t;
typedef __attribute__((ext_vector_type(8))) short short8;
typedef __attribute__((ext_vector_type(4))) short short4v;
typedef __attribute__((ext_vector_type(4))) float floatx4;

__device__ inline unsigned short f2bf(float f) {
  unsigned int u = __float_as_uint(f);
  return (unsigned short)((u + 0x7FFFu + ((u >> 16) & 1u)) >> 16);  // RNE
}

__device__ inline float fexp2(float x) {  // raw v_exp_f32 (HW is base-2)
  float r;
  asm("v_exp_f32 %0, %1" : "=v"(r) : "v"(x));
  return r;
}

// async global->LDS, 16B per lane; lds base must be wave-uniform (HW adds lane*16)
__device__ inline void ld_lds16(const void* g, void* l) {
  __builtin_amdgcn_global_load_lds((__attribute__((address_space(1))) void*)g,
                                   (__attribute__((address_space(3))) void*)l, 16, 0, 0);
}

// ---------------- fused prep: x cast + 4 weight transposes in ONE launch ----------------
__device__ inline void transp32(const float* __restrict__ in, ushort_t* __restrict__ out,
                                int R, int C, int bx, int by, int tid, float (*tile)[33]) {
  int c0 = bx * 32, r0 = by * 32;
  int x = tid & 31, y0 = tid >> 5;  // (32,8)
  for (int i = 0; i < 4; i++) {
    int r = y0 + i * 8;
    tile[r][x] = in[(size_t)(r0 + r) * C + c0 + x];
  }
  __syncthreads();
  for (int i = 0; i < 4; i++) {
    int r = y0 + i * 8;
    out[(size_t)(c0 + r) * R + r0 + x] = f2bf(tile[x][r]);
  }
}

__global__ __launch_bounds__(256) void prep(const float* __restrict__ x,
                                            ushort_t* __restrict__ xb,
                                            const float* __restrict__ Wq,
                                            const float* __restrict__ Wk,
                                            const float* __restrict__ Wv,
                                            const float* __restrict__ Wo,
                                            ushort_t* __restrict__ WT,
                                            ushort_t* __restrict__ WoT) {
  __shared__ float tile[32][33];
  int bid = blockIdx.x, tid = threadIdx.x;
  if (bid < 4096) {  // cast x fp32 -> bf16 (8 elems/thread)
    size_t i = ((size_t)bid * 256 + tid) * 8;
    float4 a = *(const float4*)(x + i);
    float4 b = *(const float4*)(x + i + 4);
    short8 o;
    o[0] = (short)f2bf(a.x); o[1] = (short)f2bf(a.y);
    o[2] = (short)f2bf(a.z); o[3] = (short)f2bf(a.w);
    o[4] = (short)f2bf(b.x); o[5] = (short)f2bf(b.y);
    o[6] = (short)f2bf(b.z); o[7] = (short)f2bf(b.w);
    *(short8*)(xb + i) = o;
    return;
  }
  bid -= 4096;
  if (bid < 4096) { transp32(Wq, WT, 2048, 2048, bid & 63, bid >> 6, tid, tile); return; }
  bid -= 4096;
  if (bid < 1024) { transp32(Wk, WT + 2048 * 2048, 2048, 512, bid & 15, bid >> 4, tid, tile); return; }
  bid -= 1024;
  if (bid < 1024) { transp32(Wv, WT + 2560 * 2048, 2048, 512, bid & 15, bid >> 4, tid, tile); return; }
  bid -= 1024;
  transp32(Wo, WoT, 2048, 2048, bid & 63, bid >> 6, tid, tile);
}

// ====== gemm_qkv: 256x256 / BK=64, 8-wave QUADRANT-PHASE core (T2+T3+T4+T5) ======
// 512 threads. Per K-tile: 4 phases; phase p = quadrant (MH[p],NH[p]) computed by ALL waves
// (per-wave 32x64 sub-block: 4 A-frag + 8 B-frag ds_read_b128, 16 MFMA). Half-residency is
// phase-dependent: p0 needs A0,B0; p1 adds A1; p2 adds B1; p3 nothing new.
// LDS 128 KiB: [dbuf][mat][half][128][64] bf16, verified XOR-swizzle. Stage order per tile:
// A0,B0,A1,B1 (one half = 2 ld_lds16/wave per phase, staged for T+1 during T).
// Counted vmcnt (T4): phase-entry vmcnt(4) leaves exactly the not-yet-needed halves in
// flight (FIFO: p0 allows A1,B1 of T; p1 allows B1+A0'; p2 allows A0'+B0'); never 0 in the
// main loop. Last tile peels to vmcnt(4)/(2)/(0). One s_barrier per phase AFTER the vmcnt
// (every wave's own stages landed => all halves landed). setprio around MFMA cluster (T5).
// Race proof: stage of T+1 (buf (T+1)&1) is issued after T-p0's barrier; any wave past that
// barrier has finished its T-1 reads of that buf (lgkmcnt before its p3 MFMAs). Bounds:
// max LDS byte = 131072 exactly; ds_read max = base+16384 per half.
__global__ __launch_bounds__(512) void gemm_qkv(const ushort_t* __restrict__ xb,
                                                const ushort_t* __restrict__ WT,
                                                ushort_t* __restrict__ qbf,
                                                float* __restrict__ outk,
                                                ushort_t* __restrict__ kbf,
                                                float* __restrict__ outv,
                                                ushort_t* __restrict__ vt,
                                                const float* __restrict__ cosP,
                                                const float* __restrict__ sinP) {
  __shared__ __align__(16) ushort_t L8[2][2][2][128][64];  // [dbuf][mat][half][row][col]
  char* Lb = (char*)L8;
  // rectangular XCD partition: nwg = 192 = 8 XCD x 24 (4m x 6n rectangle per XCD)
  int bid = blockIdx.x;
  int xcd = bid & 7, ii = bid >> 3;
  int mg = xcd >> 1, ng = xcd & 1;
  int m0 = (mg * 4 + ii / 6) * 256;
  int n0 = (ng * 6 + ii % 6) * 256;
  int tid = threadIdx.x;
  int w8 = tid >> 6, lane = tid & 63;
  int wrq = w8 >> 1, wcq = w8 & 1;  // 4 row-waves x 2 col-waves within each quadrant
  int lr = lane & 15, quad = lane >> 4;
  int sx = lr & 7;
  int srow = w8 * 16 + (lane >> 3);          // staging row within a 128-row half
  int schunk = (lane & 7) ^ (lane >> 3);     // pre-swizzled source chunk (row&7 == lane>>3)
  const char* abase = (const char*)(xb + (size_t)m0 * 2048);
  const char* bbase = (const char*)(WT + (size_t)n0 * 2048);
  floatx4 acc[4][2][4] = {};  // [phase/quadrant][i<2][j<4]

  // stage unit U of tile T: U0=A-half0, U1=B-half0, U2=A-half1, U3=B-half1
#define STG(T, U)                                                                        \
  do {                                                                                   \
    const int mat_ = (U)&1, half_ = (U) >> 1;                                            \
    const char* sp = (mat_ ? bbase : abase) + (size_t)(half_ * 128 + srow) * 4096 +      \
                     (size_t)(T)*128 + schunk * 16;                                      \
    char* dp = Lb + (((T)&1) * 65536) + mat_ * 32768 + half_ * 16384 + w8 * 2048;        \
    ld_lds16(sp, dp);                                                                    \
    ld_lds16(sp + (size_t)8 * 4096, dp + 1024);                                          \
  } while (0)

#define PH(T, P, MH_, NH_, WAITS, DOSTAGE)                                               \
  do {                                                                                   \
    asm volatile(WAITS ::: "memory");                                                    \
    const char* Ab_ = Lb + (((T)&1) * 65536) + (MH_)*16384;                              \
    const char* Bb_ = Lb + (((T)&1) * 65536) + 32768 + (NH_)*16384;                      \
    short8 af_[2][2], bf_[4][2];                                                         \
    _Pragma("unroll") for (int i = 0; i < 2; i++) {                                      \
      size_t rb = (size_t)(wrq * 32 + i * 16 + lr) * 128;                                \
      _Pragma("unroll") for (int ks = 0; ks < 2; ks++)                                   \
          af_[i][ks] = *(const short8*)(Ab_ + rb + (((ks * 4 + quad) ^ sx) << 4));       \
    }                                                                                    \
    _Pragma("unroll") for (int j = 0; j < 4; j++) {                                      \
      size_t rb = (size_t)(wcq * 64 + j * 16 + lr) * 128;                                \
      _Pragma("unroll") for (int ks = 0; ks < 2; ks++)                                   \
          bf_[j][ks] = *(const short8*)(Bb_ + rb + (((ks * 4 + quad) ^ sx) << 4));       \
    }                                                                                    \
    if (DOSTAGE) STG((T) + 1, P);                                                        \
    __builtin_amdgcn_s_setprio(1);                                                       \
    _Pragma("unroll") for (int i = 0; i < 2; i++) _Pragma("unroll") for (int j = 0;      \
                                                                         j < 4; j++) {  \
      acc[P][i][j] =                                                                     \
          __builtin_amdgcn_mfma_f32_16x16x32_bf16(af_[i][0], bf_[j][0], acc[P][i][j],    \
                                                  0, 0, 0);                              \
      acc[P][i][j] =                                                                     \
          __builtin_amdgcn_mfma_f32_16x16x32_bf16(af_[i][1], bf_[j][1], acc[P][i][j],    \
                                                  0, 0, 0);                              \
    }                                                                                    \
    __builtin_amdgcn_s_setprio(0);                                                       \
  } while (0)

  // prologue: stage all 4 units of tile 0
  STG(0, 0); STG(0, 1); STG(0, 2); STG(0, 3);

  for (int kt = 0; kt < 31; kt++) {
    PH(kt, 0, 0, 0, "s_waitcnt vmcnt(4)\n\ts_barrier", 1);
    PH(kt, 1, 1, 0, "s_waitcnt vmcnt(4)\n\ts_barrier", 1);
    PH(kt, 2, 1, 1, "s_waitcnt vmcnt(4)\n\ts_barrier", 1);
    PH(kt, 3, 0, 1, "s_barrier", 1);
  }
  // last tile: no staging; peel vmcnt 4/2/0
  PH(31, 0, 0, 0, "s_waitcnt vmcnt(4)\n\ts_barrier", 0);
  PH(31, 1, 1, 0, "s_waitcnt vmcnt(2)\n\ts_barrier", 0);
  PH(31, 2, 1, 1, "s_waitcnt vmcnt(0)\n\ts_barrier", 0);
  PH(31, 3, 0, 1, "s_barrier", 0);
#undef STG
#undef PH

  // epilogues: row = m0 + MH[p]*128 + wrq*32 + i*16 + quad*4 + r ;
  //            col = n0 + NH[p]*128 + wcq*64 + j*16 + lr
  const int MHs[4] = {0, 1, 1, 0}, NHs[4] = {0, 0, 1, 1};
  if (n0 < 2048) {  // Q + rope -> qbf, pre-scaled by 0.125*log2e
    const float QS = 0.125f * 1.4426950408889634f;
#pragma unroll
    for (int p = 0; p < 4; p++)
#pragma unroll
      for (int i = 0; i < 2; i++)
#pragma unroll
        for (int j = 0; j < 2; j++) {
          int d = j * 16 + lr;
#pragma unroll
          for (int r = 0; r < 4; r++) {
            int row = m0 + MHs[p] * 128 + wrq * 32 + i * 16 + quad * 4 + r;
            int s = row & (S_ - 1);
            float c = cosP[s * 64 + d], sn = sinP[s * 64 + d];
            float x1 = acc[p][i][j][r], x2 = acc[p][i][j + 2][r];
            size_t oo = (size_t)row * 2048 + n0 + NHs[p] * 128 + wcq * 64 + d;
            qbf[oo] = f2bf((x1 * c - x2 * sn) * QS);
            qbf[oo + 32] = f2bf((x2 * c + x1 * sn) * QS);
          }
        }
  } else if (n0 < 2560) {  // K + rope -> outk fp32 + kbf bf16 (row-swizzled)
#pragma unroll
    for (int p = 0; p < 4; p++) {
      int h = ((n0 - 2048) >> 6) + NHs[p] * 2 + wcq;
#pragma unroll
      for (int i = 0; i < 2; i++)
#pragma unroll
        for (int j = 0; j < 2; j++) {
          int d = j * 16 + lr;
#pragma unroll
          for (int r = 0; r < 4; r++) {
            int row = m0 + MHs[p] * 128 + wrq * 32 + i * 16 + quad * 4 + r;
            int s = row & (S_ - 1), b = row >> 11;
            float c = cosP[s * 64 + d], sn = sinP[s * 64 + d];
            float x1 = acc[p][i][j][r], x2 = acc[p][i][j + 2][r];
            float y1 = x1 * c - x2 * sn, y2 = x2 * c + x1 * sn;
            size_t rowb = ((size_t)(b * NKV + h) * S_ + s) * 64;
            int xr = (s & 7) << 3;
            outk[rowb + d] = y1; outk[rowb + d + 32] = y2;
            kbf[rowb + (d ^ xr)] = f2bf(y1);
            kbf[rowb + ((d + 32) ^ xr)] = f2bf(y2);
          }
        }
    }
  } else {  // V -> outv fp32 + vt bf16 (tiled+swizzled) directly: transpose_v eliminated
#pragma unroll
    for (int p = 0; p < 4; p++) {
      int h = ((n0 - 2560) >> 6) + NHs[p] * 2 + wcq;
#pragma unroll
      for (int i = 0; i < 2; i++)
#pragma unroll
        for (int j = 0; j < 4; j++) {
          int d = j * 16 + lr;
          int row0 = m0 + MHs[p] * 128 + wrq * 32 + i * 16 + quad * 4;
          int s0 = row0 & (S_ - 1), b = row0 >> 11;
#pragma unroll
          for (int r = 0; r < 4; r++)
            outv[((size_t)(b * NKV + h) * S_ + s0 + r) * 64 + d] = acc[p][i][j][r];
          int tt = s0 >> 6, s4 = s0 & 63;  // s4 is 4-aligned; XOR hits bits 3..5 only
          short4v u;
          u[0] = (short)f2bf(acc[p][i][j][0]); u[1] = (short)f2bf(acc[p][i][j][1]);
          u[2] = (short)f2bf(acc[p][i][j][2]); u[3] = (short)f2bf(acc[p][i][j][3]);
          *(short4v*)(vt + ((size_t)(b * NKV + h) * 32 + tt) * 4096 + d * 64 +
                      (s4 ^ ((d & 7) << 3))) = u;
        }
    }
  }
}

// ========== 128x128 / BK=64 GEMM core, T3 minimum 2-phase (verified, for gemm_o) ==========
__device__ __forceinline__ void gemm128_core(const ushort_t* __restrict__ Ag,   // + m0*2048
                                             const ushort_t* __restrict__ Bg,   // + n0*2048
                                             floatx4 (&acc)[4][4]) {
  __shared__ __align__(16) ushort_t As[2][128][64];
  __shared__ __align__(16) ushort_t Bs[2][128][64];
  int tid = threadIdx.x;
  int w = tid >> 6, lane = tid & 63;
  int wm = (w >> 1) * 64, wn = (w & 1) * 64;
  int lr = lane & 15, quad = lane >> 4;
  int sx = lr & 7;
  char* Asb = (char*)As;
  char* Bsb = (char*)Bs;

  size_t so[4];
#pragma unroll
  for (int s = 0; s < 4; s++)
    so[s] = (size_t)(w * 32 + s * 8 + (lane >> 3)) * 4096 + (size_t)(((lane & 7) ^ (lane >> 3)) * 16);
  const char* abase = (const char*)Ag;
  const char* bbase = (const char*)Bg;

#define STAGE128(buf, kt)                                          \
  do {                                                             \
    size_t ko = (size_t)(kt) * 128;                                \
    char* Ad = Asb + (buf) * 16384 + w * 4096;                     \
    char* Bd = Bsb + (buf) * 16384 + w * 4096;                     \
    _Pragma("unroll") for (int s = 0; s < 4; s++) {                \
      ld_lds16(abase + so[s] + ko, Ad + s * 1024);                 \
      ld_lds16(bbase + so[s] + ko, Bd + s * 1024);                 \
    }                                                              \
  } while (0)

  STAGE128(0, 0);
  __syncthreads();

  int cur = 0;
  for (int kt = 0; kt < 32; kt++) {
    if (kt < 31) STAGE128(cur ^ 1, kt + 1);  // issue BEFORE compute; lands by tile-end sync
    const char* Ab = Asb + cur * 16384;
    const char* Bb = Bsb + cur * 16384;
    short8 af[4][2], bfr[4][2];
#pragma unroll
    for (int i = 0; i < 4; i++) {
      size_t rb = (size_t)(wm + i * 16 + lr) * 128;
#pragma unroll
      for (int ks = 0; ks < 2; ks++)
        af[i][ks] = *(const short8*)(Ab + rb + (((ks * 4 + quad) ^ sx) << 4));
    }
#pragma unroll
    for (int j = 0; j < 4; j++) {
      size_t rb = (size_t)(wn + j * 16 + lr) * 128;
#pragma unroll
      for (int ks = 0; ks < 2; ks++)
        bfr[j][ks] = *(const short8*)(Bb + rb + (((ks * 4 + quad) ^ sx) << 4));
    }
#pragma unroll
    for (int i = 0; i < 4; i++)
#pragma unroll
      for (int j = 0; j < 4; j++) {
        acc[i][j] = __builtin_amdgcn_mfma_f32_16x16x32_bf16(af[i][0], bfr[j][0], acc[i][j], 0, 0, 0);
        acc[i][j] = __builtin_amdgcn_mfma_f32_16x16x32_bf16(af[i][1], bfr[j][1], acc[i][j], 0, 0, 0);
      }
    __syncthreads();  // vmcnt(0)+lgkmcnt(0)+barrier: kt+1 landed, all reads of cur done
    cur ^= 1;
  }
#undef STAGE128
}

// ---------------- O GEMM: ctx(qbf) @ WoT^T -> y fp32, 128^2 tiles ----------------
__global__ __launch_bounds__(256) void gemm_o(const ushort_t* __restrict__ ctx,
                                              const ushort_t* __restrict__ WoT,
                                              float* __restrict__ y) {
  // rectangular XCD partition: each XCD owns an 8m x 8n rectangle
  int o = blockIdx.y * 16 + blockIdx.x;   // nwg = 512 = 8 * 64
  int xcd = o & 7, i = o >> 3;            // i in [0,64)
  int mg = xcd >> 1, ng = xcd & 1;
  int m0 = (mg * 8 + (i >> 3)) * 128;
  int n0 = (ng * 8 + (i & 7)) * 128;
  int tid = threadIdx.x;
  int w = tid >> 6, lane = tid & 63;
  int wm = (w >> 1) * 64, wn = (w & 1) * 64;
  int lr = lane & 15, quad = lane >> 4;

  floatx4 acc[4][4] = {};
  gemm128_core(ctx + (size_t)m0 * 2048, WoT + (size_t)n0 * 2048, acc);

#pragma unroll
  for (int i2 = 0; i2 < 4; i2++)
#pragma unroll
    for (int j = 0; j < 4; j++) {
      int row = m0 + wm + i2 * 16 + quad * 4;
      int col = n0 + wn + j * 16 + lr;
#pragma unroll
      for (int r = 0; r < 4; r++)
        y[(size_t)(row + r) * 2048 + col] = acc[i2][j][r];
    }
}

// ---------------- MFMA flash attention: 2-phase DMA pipeline + setprio (verified r8) ------
__global__ __launch_bounds__(256, 4) void attn2(ushort_t* __restrict__ q,
                                                const ushort_t* __restrict__ k,
                                                const ushort_t* __restrict__ vt) {
  __shared__ __align__(16) ushort_t KV[2][2][64][64];  // [buf][K/V][row][col], swizzled content
  __shared__ __align__(16) ushort_t Ps[4][16][64];     // per-wave P^T, swizzled
  int bh = blockIdx.x;
  int qt = 31 - blockIdx.y;  // longest first
  int b = bh >> 5, h = bh & 31, g = h >> 2;
  int tid = threadIdx.x;
  int w = tid >> 6, lane = tid & 63;
  int lr = lane & 15, quad = lane >> 4;

  int qg = qt * 64 + w * 16 + lr;  // this lane's query row
  short8 aq0, aq1;                 // Q B-frag (Q^T operand), pre-scaled 0.125*log2e
  {
    const ushort_t* qp = q + ((size_t)(b * S_ + qg) * NH + h) * HD;
    aq0 = *(const short8*)(qp + quad * 8);
    aq1 = *(const short8*)(qp + 32 + quad * 8);
  }
  floatx4 od[4] = {};  // O^T[d=dn*16+quad*4+r][qrow=lr]
  float mi = -INFINITY, li = 0.f;

  const char* ksrc = (const char*)(k + (size_t)(b * NKV + g) * S_ * HD) + w * 2048 + lane * 16;
  const char* vsrc = (const char*)(vt + (size_t)(b * NKV + g) * S_ * HD) + w * 2048 + lane * 16;
  char* dB = (char*)&KV[0][0][0][0] + w * 2048;  // K region; +8192 = V region; +16384 = buf1

  int sw = (lr & 7) << 4;
  int ro0 = (quad * 16) ^ sw;
  int ro1 = (64 + quad * 16) ^ sw;
  char* Pw = (char*)&Ps[0][0][0] + w * 2048;

  // prologue: stage tile 0 -> buf 0
  ld_lds16(ksrc, dB);
  ld_lds16(ksrc + 1024, dB + 1024);
  ld_lds16(vsrc, dB + 8192);
  ld_lds16(vsrc + 1024, dB + 8192 + 1024);
  asm volatile("s_waitcnt vmcnt(0)" ::: "memory");
  __syncthreads();

  int cur = 0;
  for (int t = 0; t <= qt; t++) {
    if (t < qt) {
      const char* kn = ksrc + (size_t)(t + 1) * 8192;
      const char* vn = vsrc + (size_t)(t + 1) * 8192;
      char* d = dB + (cur ^ 1) * 16384;
      ld_lds16(kn, d); ld_lds16(kn + 1024, d + 1024);
      ld_lds16(vn, d + 8192); ld_lds16(vn + 1024, d + 8192 + 1024);
    }
    const char* Kb = (const char*)&KV[cur][0][0][0];
    const char* Vb = (const char*)&KV[cur][1][0][0];
    floatx4 sc[4];
    __builtin_amdgcn_s_setprio(1);
#pragma unroll
    for (int kn = 0; kn < 4; kn++) {
      short8 a0 = *(const short8*)(Kb + (kn * 16 + lr) * 128 + ro0);
      short8 a1 = *(const short8*)(Kb + (kn * 16 + lr) * 128 + ro1);
      floatx4 c = {};
      c = __builtin_amdgcn_mfma_f32_16x16x32_bf16(a0, aq0, c, 0, 0, 0);
      c = __builtin_amdgcn_mfma_f32_16x16x32_bf16(a1, aq1, c, 0, 0, 0);
      sc[kn] = c;
    }
    __builtin_amdgcn_s_setprio(0);
    float pv[16];
#pragma unroll
    for (int kn = 0; kn < 4; kn++)
#pragma unroll
      for (int r = 0; r < 4; r++) pv[kn * 4 + r] = sc[kn][r];
    if (t == qt) {  // causal mask: diagonal tile only
#pragma unroll
      for (int e = 0; e < 16; e++) {
        int kg = t * 64 + (e >> 2) * 16 + quad * 4 + (e & 3);
        if (kg > qg) pv[e] = -INFINITY;
      }
    }
    float mx = pv[0];
#pragma unroll
    for (int e = 1; e < 16; e++) mx = fmaxf(mx, pv[e]);
    mx = fmaxf(mx, __shfl_xor(mx, 16));
    mx = fmaxf(mx, __shfl_xor(mx, 32));
    if (__any(mx > mi + 11.5f)) {  // defer-max (T13), log2 units
      float mn = fmaxf(mi, mx);
      float al = fexp2(mi - mn);
      li *= al;
#pragma unroll
      for (int dn = 0; dn < 4; dn++) {
        od[dn][0] *= al; od[dn][1] *= al; od[dn][2] *= al; od[dn][3] *= al;
      }
      mi = mn;
    }
    float ps = 0.f;
#pragma unroll
    for (int e = 0; e < 16; e++) {
      pv[e] = fexp2(pv[e] - mi);
      ps += pv[e];
    }
    ps += __shfl_xor(ps, 16);
    ps += __shfl_xor(ps, 32);
    li += ps;
#pragma unroll
    for (int kn = 0; kn < 4; kn++) {
      unsigned int u0, u1;
      asm("v_cvt_pk_bf16_f32 %0, %1, %2" : "=v"(u0) : "v"(pv[kn * 4 + 0]), "v"(pv[kn * 4 + 1]));
      asm("v_cvt_pk_bf16_f32 %0, %1, %2" : "=v"(u1) : "v"(pv[kn * 4 + 2]), "v"(pv[kn * 4 + 3]));
      uint2 uu; uu.x = u0; uu.y = u1;
      *(uint2*)(Pw + lr * 128 + ((kn * 32 + quad * 8) ^ sw)) = uu;
    }
    short8 pb0 = *(const short8*)(Pw + lr * 128 + ro0);
    short8 pb1 = *(const short8*)(Pw + lr * 128 + ro1);
    __builtin_amdgcn_s_setprio(1);
#pragma unroll
    for (int dn = 0; dn < 4; dn++) {
      short8 va = *(const short8*)(Vb + (dn * 16 + lr) * 128 + ro0);
      short8 vb = *(const short8*)(Vb + (dn * 16 + lr) * 128 + ro1);
      od[dn] = __builtin_amdgcn_mfma_f32_16x16x32_bf16(va, pb0, od[dn], 0, 0, 0);
      od[dn] = __builtin_amdgcn_mfma_f32_16x16x32_bf16(vb, pb1, od[dn], 0, 0, 0);
    }
    __builtin_amdgcn_s_setprio(0);
    asm volatile("s_waitcnt vmcnt(0)" ::: "memory");
    __syncthreads();
    cur ^= 1;
  }
  float inv = 1.f / li;
  ushort_t* outp = q + ((size_t)(b * S_ + qg) * NH + h) * HD;
#pragma unroll
  for (int dn = 0; dn < 4; dn++) {
    short4v u;
    u[0] = (short)f2bf(od[dn][0] * inv); u[1] = (short)f2bf(od[dn][1] * inv);
    u[2] = (short)f2bf(od[dn][2] * inv); u[3] = (short)f2bf(od[dn][3] * inv);
    *(short4v*)(outp + dn * 16 + quad * 4) = u;
  }
}

extern "C" void kernel_launch(void* const* d_in, const int* in_sizes, int n_in,
                              void* d_out, int out_size, void* d_ws, size_t ws_size,
                              hipStream_t stream) {
  const float* x = (const float*)d_in[0];
  const float* cosT = (const float*)d_in[2];
  const float* sinT = (const float*)d_in[3];
  const float* Wq = (const float*)d_in[4];
  const float* Wk = (const float*)d_in[5];
  const float* Wv = (const float*)d_in[6];
  const float* Wo = (const float*)d_in[7];

  char* ws = (char*)d_ws;
  ushort_t* WT = (ushort_t*)(ws);                 // 12 MB (3072, 2048): Wq^T | Wk^T | Wv^T
  ushort_t* WoT = (ushort_t*)(ws + 12582912);     //  8 MB (2048, 2048)
  ushort_t* xb = (ushort_t*)(ws + 20971520);      // 16 MB (M, 2048) bf16
  ushort_t* qbf = (ushort_t*)(ws + 37748736);     // 16 MB (B,S,NH,HD); ctx in-place
  ushort_t* kbf = (ushort_t*)(ws + 54525952);     //  4 MB (B,NKV,S,HD) swizzled
  ushort_t* vt = (ushort_t*)(ws + 58720256);      //  4 MB tiled (bg,S/64,HD,64) swizzled

  float* y = (float*)d_out;                            // (B,S,E) fp32
  float* outk = y + (size_t)M_ * E_;                   // (B,NKV,S,HD) fp32
  float* outv = outk + (size_t)B_ * NKV * S_ * HD;     // (B,NKV,S,HD) fp32

  prep<<<dim3(14336), 256, 0, stream>>>(x, xb, Wq, Wk, Wv, Wo, WT, WoT);

  gemm_qkv<<<dim3(192), 512, 0, stream>>>(xb, WT, qbf, outk, kbf, outv, vt, cosT, sinT);

  attn2<<<dim3(64, 32), 256, 0, stream>>>(qbf, kbf, vt);

  gemm_o<<<dim3(16, 32), 256, 0, stream>>>(qbf, WoT, y);
}

// Round 10
// 303.862 us; speedup vs baseline: 1.1994x; 1.0155x over previous
//
#include <hip/hip_runtime.h>
#include <hip/hip_bf16.h>
#include <math.h>

#define NH 32
#define NKV 8
#define HD 64
#define B_ 2
#define S_ 2048
#define E_ 2048
#define M_ 4096   // B_*S_

typedef unsigned short ushort_t;
typedef __attribute__((ext_vector_type(8))) short short8;
typedef __attribute__((ext_vector_type(4))) short short4v;
typedef __attribute__((ext_vector_type(4))) float floatx4;

__device__ inline unsigned short f2bf(float f) {
  unsigned int u = __float_as_uint(f);
  return (unsigned short)((u + 0x7FFFu + ((u >> 16) & 1u)) >> 16);  // RNE
}

__device__ inline float fexp2(float x) {  // raw v_exp_f32 (HW is base-2)
  float r;
  asm("v_exp_f32 %0, %1" : "=v"(r) : "v"(x));
  return r;
}

// async global->LDS, 16B per lane; lds base must be wave-uniform (HW adds lane*16)
__device__ inline void ld_lds16(const void* g, void* l) {
  __builtin_amdgcn_global_load_lds((__attribute__((address_space(1))) void*)g,
                                   (__attribute__((address_space(3))) void*)l, 16, 0, 0);
}

// ---------------- fused prep: x cast + 4 weight transposes in ONE launch ----------------
__device__ inline void transp32(const float* __restrict__ in, ushort_t* __restrict__ out,
                                int R, int C, int bx, int by, int tid, float (*tile)[33]) {
  int c0 = bx * 32, r0 = by * 32;
  int x = tid & 31, y0 = tid >> 5;  // (32,8)
  for (int i = 0; i < 4; i++) {
    int r = y0 + i * 8;
    tile[r][x] = in[(size_t)(r0 + r) * C + c0 + x];
  }
  __syncthreads();
  for (int i = 0; i < 4; i++) {
    int r = y0 + i * 8;
    out[(size_t)(c0 + r) * R + r0 + x] = f2bf(tile[x][r]);
  }
}

__global__ __launch_bounds__(256) void prep(const float* __restrict__ x,
                                            ushort_t* __restrict__ xb,
                                            const float* __restrict__ Wq,
                                            const float* __restrict__ Wk,
                                            const float* __restrict__ Wv,
                                            const float* __restrict__ Wo,
                                            ushort_t* __restrict__ WT,
                                            ushort_t* __restrict__ WoT) {
  __shared__ float tile[32][33];
  int bid = blockIdx.x, tid = threadIdx.x;
  if (bid < 4096) {  // cast x fp32 -> bf16 (8 elems/thread)
    size_t i = ((size_t)bid * 256 + tid) * 8;
    float4 a = *(const float4*)(x + i);
    float4 b = *(const float4*)(x + i + 4);
    short8 o;
    o[0] = (short)f2bf(a.x); o[1] = (short)f2bf(a.y);
    o[2] = (short)f2bf(a.z); o[3] = (short)f2bf(a.w);
    o[4] = (short)f2bf(b.x); o[5] = (short)f2bf(b.y);
    o[6] = (short)f2bf(b.z); o[7] = (short)f2bf(b.w);
    *(short8*)(xb + i) = o;
    return;
  }
  bid -= 4096;
  if (bid < 4096) { transp32(Wq, WT, 2048, 2048, bid & 63, bid >> 6, tid, tile); return; }
  bid -= 4096;
  if (bid < 1024) { transp32(Wk, WT + 2048 * 2048, 2048, 512, bid & 15, bid >> 4, tid, tile); return; }
  bid -= 1024;
  if (bid < 1024) { transp32(Wv, WT + 2560 * 2048, 2048, 512, bid & 15, bid >> 4, tid, tile); return; }
  bid -= 1024;
  transp32(Wo, WoT, 2048, 2048, bid & 63, bid >> 6, tid, tile);
}

// ====== gemm_qkv: 256x256 / BK=64, 8-wave QUADRANT-PHASE core (T2+T3+T4+T5, verified r9) ======
__global__ __launch_bounds__(512) void gemm_qkv(const ushort_t* __restrict__ xb,
                                                const ushort_t* __restrict__ WT,
                                                ushort_t* __restrict__ qbf,
                                                float* __restrict__ outk,
                                                ushort_t* __restrict__ kbf,
                                                float* __restrict__ outv,
                                                ushort_t* __restrict__ vt,
                                                const float* __restrict__ cosP,
                                                const float* __restrict__ sinP) {
  __shared__ __align__(16) ushort_t L8[2][2][2][128][64];  // [dbuf][mat][half][row][col]
  char* Lb = (char*)L8;
  // rectangular XCD partition: nwg = 192 = 8 XCD x 24 (4m x 6n rectangle per XCD)
  int bid = blockIdx.x;
  int xcd = bid & 7, ii = bid >> 3;
  int mg = xcd >> 1, ng = xcd & 1;
  int m0 = (mg * 4 + ii / 6) * 256;
  int n0 = (ng * 6 + ii % 6) * 256;
  int tid = threadIdx.x;
  int w8 = tid >> 6, lane = tid & 63;
  int wrq = w8 >> 1, wcq = w8 & 1;  // 4 row-waves x 2 col-waves within each quadrant
  int lr = lane & 15, quad = lane >> 4;
  int sx = lr & 7;
  int srow = w8 * 16 + (lane >> 3);          // staging row within a 128-row half
  int schunk = (lane & 7) ^ (lane >> 3);     // pre-swizzled source chunk (row&7 == lane>>3)
  const char* abase = (const char*)(xb + (size_t)m0 * 2048);
  const char* bbase = (const char*)(WT + (size_t)n0 * 2048);
  floatx4 acc[4][2][4] = {};  // [phase/quadrant][i<2][j<4]

#define STG(T, U)                                                                        \
  do {                                                                                   \
    const int mat_ = (U)&1, half_ = (U) >> 1;                                            \
    const char* sp = (mat_ ? bbase : abase) + (size_t)(half_ * 128 + srow) * 4096 +      \
                     (size_t)(T)*128 + schunk * 16;                                      \
    char* dp = Lb + (((T)&1) * 65536) + mat_ * 32768 + half_ * 16384 + w8 * 2048;        \
    ld_lds16(sp, dp);                                                                    \
    ld_lds16(sp + (size_t)8 * 4096, dp + 1024);                                          \
  } while (0)

#define PH(T, P, MH_, NH_, WAITS, DOSTAGE)                                               \
  do {                                                                                   \
    asm volatile(WAITS ::: "memory");                                                    \
    const char* Ab_ = Lb + (((T)&1) * 65536) + (MH_)*16384;                              \
    const char* Bb_ = Lb + (((T)&1) * 65536) + 32768 + (NH_)*16384;                      \
    short8 af_[2][2], bf_[4][2];                                                         \
    _Pragma("unroll") for (int i = 0; i < 2; i++) {                                      \
      size_t rb = (size_t)(wrq * 32 + i * 16 + lr) * 128;                                \
      _Pragma("unroll") for (int ks = 0; ks < 2; ks++)                                   \
          af_[i][ks] = *(const short8*)(Ab_ + rb + (((ks * 4 + quad) ^ sx) << 4));       \
    }                                                                                    \
    _Pragma("unroll") for (int j = 0; j < 4; j++) {                                      \
      size_t rb = (size_t)(wcq * 64 + j * 16 + lr) * 128;                                \
      _Pragma("unroll") for (int ks = 0; ks < 2; ks++)                                   \
          bf_[j][ks] = *(const short8*)(Bb_ + rb + (((ks * 4 + quad) ^ sx) << 4));       \
    }                                                                                    \
    if (DOSTAGE) STG((T) + 1, P);                                                        \
    __builtin_amdgcn_s_setprio(1);                                                       \
    _Pragma("unroll") for (int i = 0; i < 2; i++) _Pragma("unroll") for (int j = 0;      \
                                                                         j < 4; j++) {  \
      acc[P][i][j] =                                                                     \
          __builtin_amdgcn_mfma_f32_16x16x32_bf16(af_[i][0], bf_[j][0], acc[P][i][j],    \
                                                  0, 0, 0);                              \
      acc[P][i][j] =                                                                     \
          __builtin_amdgcn_mfma_f32_16x16x32_bf16(af_[i][1], bf_[j][1], acc[P][i][j],    \
                                                  0, 0, 0);                              \
    }                                                                                    \
    __builtin_amdgcn_s_setprio(0);                                                       \
  } while (0)

  // prologue: stage all 4 units of tile 0
  STG(0, 0); STG(0, 1); STG(0, 2); STG(0, 3);

  for (int kt = 0; kt < 31; kt++) {
    PH(kt, 0, 0, 0, "s_waitcnt vmcnt(4)\n\ts_barrier", 1);
    PH(kt, 1, 1, 0, "s_waitcnt vmcnt(4)\n\ts_barrier", 1);
    PH(kt, 2, 1, 1, "s_waitcnt vmcnt(4)\n\ts_barrier", 1);
    PH(kt, 3, 0, 1, "s_barrier", 1);
  }
  // last tile: no staging; peel vmcnt 4/2/0
  PH(31, 0, 0, 0, "s_waitcnt vmcnt(4)\n\ts_barrier", 0);
  PH(31, 1, 1, 0, "s_waitcnt vmcnt(2)\n\ts_barrier", 0);
  PH(31, 2, 1, 1, "s_waitcnt vmcnt(0)\n\ts_barrier", 0);
  PH(31, 3, 0, 1, "s_barrier", 0);
#undef STG
#undef PH

  // epilogues: row = m0 + MH[p]*128 + wrq*32 + i*16 + quad*4 + r ;
  //            col = n0 + NH[p]*128 + wcq*64 + j*16 + lr
  const int MHs[4] = {0, 1, 1, 0}, NHs[4] = {0, 0, 1, 1};
  if (n0 < 2048) {  // Q + rope -> qbf, pre-scaled by 0.125*log2e
    const float QS = 0.125f * 1.4426950408889634f;
#pragma unroll
    for (int p = 0; p < 4; p++)
#pragma unroll
      for (int i = 0; i < 2; i++)
#pragma unroll
        for (int j = 0; j < 2; j++) {
          int d = j * 16 + lr;
#pragma unroll
          for (int r = 0; r < 4; r++) {
            int row = m0 + MHs[p] * 128 + wrq * 32 + i * 16 + quad * 4 + r;
            int s = row & (S_ - 1);
            float c = cosP[s * 64 + d], sn = sinP[s * 64 + d];
            float x1 = acc[p][i][j][r], x2 = acc[p][i][j + 2][r];
            size_t oo = (size_t)row * 2048 + n0 + NHs[p] * 128 + wcq * 64 + d;
            qbf[oo] = f2bf((x1 * c - x2 * sn) * QS);
            qbf[oo + 32] = f2bf((x2 * c + x1 * sn) * QS);
          }
        }
  } else if (n0 < 2560) {  // K + rope -> outk fp32 + kbf bf16 (row-swizzled)
#pragma unroll
    for (int p = 0; p < 4; p++) {
      int h = ((n0 - 2048) >> 6) + NHs[p] * 2 + wcq;
#pragma unroll
      for (int i = 0; i < 2; i++)
#pragma unroll
        for (int j = 0; j < 2; j++) {
          int d = j * 16 + lr;
#pragma unroll
          for (int r = 0; r < 4; r++) {
            int row = m0 + MHs[p] * 128 + wrq * 32 + i * 16 + quad * 4 + r;
            int s = row & (S_ - 1), b = row >> 11;
            float c = cosP[s * 64 + d], sn = sinP[s * 64 + d];
            float x1 = acc[p][i][j][r], x2 = acc[p][i][j + 2][r];
            float y1 = x1 * c - x2 * sn, y2 = x2 * c + x1 * sn;
            size_t rowb = ((size_t)(b * NKV + h) * S_ + s) * 64;
            int xr = (s & 7) << 3;
            outk[rowb + d] = y1; outk[rowb + d + 32] = y2;
            kbf[rowb + (d ^ xr)] = f2bf(y1);
            kbf[rowb + ((d + 32) ^ xr)] = f2bf(y2);
          }
        }
    }
  } else {  // V -> outv fp32 + vt bf16 (tiled+swizzled) directly
#pragma unroll
    for (int p = 0; p < 4; p++) {
      int h = ((n0 - 2560) >> 6) + NHs[p] * 2 + wcq;
#pragma unroll
      for (int i = 0; i < 2; i++)
#pragma unroll
        for (int j = 0; j < 4; j++) {
          int d = j * 16 + lr;
          int row0 = m0 + MHs[p] * 128 + wrq * 32 + i * 16 + quad * 4;
          int s0 = row0 & (S_ - 1), b = row0 >> 11;
#pragma unroll
          for (int r = 0; r < 4; r++)
            outv[((size_t)(b * NKV + h) * S_ + s0 + r) * 64 + d] = acc[p][i][j][r];
          int tt = s0 >> 6, s4 = s0 & 63;  // s4 is 4-aligned; XOR hits bits 3..5 only
          short4v u;
          u[0] = (short)f2bf(acc[p][i][j][0]); u[1] = (short)f2bf(acc[p][i][j][1]);
          u[2] = (short)f2bf(acc[p][i][j][2]); u[3] = (short)f2bf(acc[p][i][j][3]);
          *(short4v*)(vt + ((size_t)(b * NKV + h) * 32 + tt) * 4096 + d * 64 +
                      (s4 ^ ((d & 7) << 3))) = u;
        }
    }
  }
}

// ========== 128x128 / BK=64 GEMM core, T3 minimum 2-phase (verified, for gemm_o) ==========
__device__ __forceinline__ void gemm128_core(const ushort_t* __restrict__ Ag,   // + m0*2048
                                             const ushort_t* __restrict__ Bg,   // + n0*2048
                                             floatx4 (&acc)[4][4]) {
  __shared__ __align__(16) ushort_t As[2][128][64];
  __shared__ __align__(16) ushort_t Bs[2][128][64];
  int tid = threadIdx.x;
  int w = tid >> 6, lane = tid & 63;
  int wm = (w >> 1) * 64, wn = (w & 1) * 64;
  int lr = lane & 15, quad = lane >> 4;
  int sx = lr & 7;
  char* Asb = (char*)As;
  char* Bsb = (char*)Bs;

  size_t so[4];
#pragma unroll
  for (int s = 0; s < 4; s++)
    so[s] = (size_t)(w * 32 + s * 8 + (lane >> 3)) * 4096 + (size_t)(((lane & 7) ^ (lane >> 3)) * 16);
  const char* abase = (const char*)Ag;
  const char* bbase = (const char*)Bg;

#define STAGE128(buf, kt)                                          \
  do {                                                             \
    size_t ko = (size_t)(kt) * 128;                                \
    char* Ad = Asb + (buf) * 16384 + w * 4096;                     \
    char* Bd = Bsb + (buf) * 16384 + w * 4096;                     \
    _Pragma("unroll") for (int s = 0; s < 4; s++) {                \
      ld_lds16(abase + so[s] + ko, Ad + s * 1024);                 \
      ld_lds16(bbase + so[s] + ko, Bd + s * 1024);                 \
    }                                                              \
  } while (0)

  STAGE128(0, 0);
  __syncthreads();

  int cur = 0;
  for (int kt = 0; kt < 32; kt++) {
    if (kt < 31) STAGE128(cur ^ 1, kt + 1);  // issue BEFORE compute; lands by tile-end sync
    const char* Ab = Asb + cur * 16384;
    const char* Bb = Bsb + cur * 16384;
    short8 af[4][2], bfr[4][2];
#pragma unroll
    for (int i = 0; i < 4; i++) {
      size_t rb = (size_t)(wm + i * 16 + lr) * 128;
#pragma unroll
      for (int ks = 0; ks < 2; ks++)
        af[i][ks] = *(const short8*)(Ab + rb + (((ks * 4 + quad) ^ sx) << 4));
    }
#pragma unroll
    for (int j = 0; j < 4; j++) {
      size_t rb = (size_t)(wn + j * 16 + lr) * 128;
#pragma unroll
      for (int ks = 0; ks < 2; ks++)
        bfr[j][ks] = *(const short8*)(Bb + rb + (((ks * 4 + quad) ^ sx) << 4));
    }
#pragma unroll
    for (int i = 0; i < 4; i++)
#pragma unroll
      for (int j = 0; j < 4; j++) {
        acc[i][j] = __builtin_amdgcn_mfma_f32_16x16x32_bf16(af[i][0], bfr[j][0], acc[i][j], 0, 0, 0);
        acc[i][j] = __builtin_amdgcn_mfma_f32_16x16x32_bf16(af[i][1], bfr[j][1], acc[i][j], 0, 0, 0);
      }
    __syncthreads();  // vmcnt(0)+lgkmcnt(0)+barrier: kt+1 landed, all reads of cur done
    cur ^= 1;
  }
#undef STAGE128
}

// ---------------- O GEMM: ctx(qbf) @ WoT^T -> y fp32, 128^2 tiles ----------------
__global__ __launch_bounds__(256) void gemm_o(const ushort_t* __restrict__ ctx,
                                              const ushort_t* __restrict__ WoT,
                                              float* __restrict__ y) {
  // rectangular XCD partition: each XCD owns an 8m x 8n rectangle
  int o = blockIdx.y * 16 + blockIdx.x;   // nwg = 512 = 8 * 64
  int xcd = o & 7, i = o >> 3;            // i in [0,64)
  int mg = xcd >> 1, ng = xcd & 1;
  int m0 = (mg * 8 + (i >> 3)) * 128;
  int n0 = (ng * 8 + (i & 7)) * 128;
  int tid = threadIdx.x;
  int w = tid >> 6, lane = tid & 63;
  int wm = (w >> 1) * 64, wn = (w & 1) * 64;
  int lr = lane & 15, quad = lane >> 4;

  floatx4 acc[4][4] = {};
  gemm128_core(ctx + (size_t)m0 * 2048, WoT + (size_t)n0 * 2048, acc);

#pragma unroll
  for (int i2 = 0; i2 < 4; i2++)
#pragma unroll
    for (int j = 0; j < 4; j++) {
      int row = m0 + wm + i2 * 16 + quad * 4;
      int col = n0 + wn + j * 16 + lr;
#pragma unroll
      for (int r = 0; r < 4; r++)
        y[(size_t)(row + r) * 2048 + col] = acc[i2][j][r];
    }
}

// ---------------- MFMA flash attention v6: QBLK=128 (2 Q-frags/wave, lower/upper split) ----
// Per block: 128 q-rows of one (b,h); per wave: Q0 rows qi*128+w*16+lr, Q1 rows +64.
// K/V staging unchanged (64-key tiles, 32KB dbuf); Ps grows to [4][2][16][64] (48KB total,
// 3 blocks/CU). Iteration count HALVES (fixed sync/DMA cost amortized 2x). Causality is
// block-uniform: tile t==2qi -> Q0 diag-masked; final tile t==2qi+1 -> Q0 fully masked
// (SKIPPED: half-cost iter), Q1 diag-masked. VGPR-lean order: QK0->SM0->st0->QK1->SM1->st1->PV.
__global__ __launch_bounds__(256, 3) void attn2(ushort_t* __restrict__ q,
                                                const ushort_t* __restrict__ k,
                                                const ushort_t* __restrict__ vt) {
  __shared__ __align__(16) ushort_t KV[2][2][64][64];  // [buf][K/V][row][col], swizzled content
  __shared__ __align__(16) ushort_t Ps[4][2][16][64];  // per-wave, per-Qfrag P^T, swizzled
  int bh = blockIdx.x;
  int qi = 15 - blockIdx.y;  // longest first
  int b = bh >> 5, h = bh & 31, g = h >> 2;
  int tid = threadIdx.x;
  int w = tid >> 6, lane = tid & 63;
  int lr = lane & 15, quad = lane >> 4;

  int qg0 = qi * 128 + w * 16 + lr;  // Q0 row (lower half)
  int qg1 = qg0 + 64;                // Q1 row (upper half)
  short8 a00, a01, a10, a11;         // Q B-frags, pre-scaled 0.125*log2e
  {
    const ushort_t* qp0 = q + ((size_t)(b * S_ + qg0) * NH + h) * HD;
    const ushort_t* qp1 = q + ((size_t)(b * S_ + qg1) * NH + h) * HD;
    a00 = *(const short8*)(qp0 + quad * 8);
    a01 = *(const short8*)(qp0 + 32 + quad * 8);
    a10 = *(const short8*)(qp1 + quad * 8);
    a11 = *(const short8*)(qp1 + 32 + quad * 8);
  }
  floatx4 od0[4] = {}, od1[4] = {};
  float mi0 = -INFINITY, li0 = 0.f, mi1 = -INFINITY, li1 = 0.f;

  const char* ksrc = (const char*)(k + (size_t)(b * NKV + g) * S_ * HD) + w * 2048 + lane * 16;
  const char* vsrc = (const char*)(vt + (size_t)(b * NKV + g) * S_ * HD) + w * 2048 + lane * 16;
  char* dB = (char*)&KV[0][0][0][0] + w * 2048;  // K region; +8192 = V region; +16384 = buf1

  int sw = (lr & 7) << 4;
  int ro0 = (quad * 16) ^ sw;
  int ro1 = (64 + quad * 16) ^ sw;
  char* Pw = (char*)&Ps[0][0][0][0] + w * 4096;  // frag f at +f*2048

  // prologue: stage tile 0 -> buf 0
  ld_lds16(ksrc, dB);
  ld_lds16(ksrc + 1024, dB + 1024);
  ld_lds16(vsrc, dB + 8192);
  ld_lds16(vsrc + 1024, dB + 8192 + 1024);
  asm volatile("s_waitcnt vmcnt(0)" ::: "memory");
  __syncthreads();

  int T = 2 * qi + 2;
  int cur = 0;
  for (int t = 0; t < T; t++) {
    if (t + 1 < T) {
      const char* kn = ksrc + (size_t)(t + 1) * 8192;
      const char* vn = vsrc + (size_t)(t + 1) * 8192;
      char* d = dB + (cur ^ 1) * 16384;
      ld_lds16(kn, d); ld_lds16(kn + 1024, d + 1024);
      ld_lds16(vn, d + 8192); ld_lds16(vn + 1024, d + 8192 + 1024);
    }
    const char* Kb = (const char*)&KV[cur][0][0][0];
    const char* Vb = (const char*)&KV[cur][1][0][0];
    bool dq0 = (t == 2 * qi);       // Q0 diagonal tile
    bool skip0 = (t == 2 * qi + 1); // Q0 fully masked (final tile)
    // ---- Q0: QK -> softmax -> P store (block-uniform skip on final tile) ----
    if (!skip0) {
      floatx4 sc[4];
      __builtin_amdgcn_s_setprio(1);
#pragma unroll
      for (int kn = 0; kn < 4; kn++) {
        short8 k0 = *(const short8*)(Kb + (kn * 16 + lr) * 128 + ro0);
        short8 k1 = *(const short8*)(Kb + (kn * 16 + lr) * 128 + ro1);
        floatx4 c = {};
        c = __builtin_amdgcn_mfma_f32_16x16x32_bf16(k0, a00, c, 0, 0, 0);
        c = __builtin_amdgcn_mfma_f32_16x16x32_bf16(k1, a01, c, 0, 0, 0);
        sc[kn] = c;
      }
      __builtin_amdgcn_s_setprio(0);
      float pv[16];
#pragma unroll
      for (int kn = 0; kn < 4; kn++)
#pragma unroll
        for (int r = 0; r < 4; r++) pv[kn * 4 + r] = sc[kn][r];
      if (dq0) {
#pragma unroll
        for (int e = 0; e < 16; e++) {
          int kg = t * 64 + (e >> 2) * 16 + quad * 4 + (e & 3);
          if (kg > qg0) pv[e] = -INFINITY;
        }
      }
      float mx = pv[0];
#pragma unroll
      for (int e = 1; e < 16; e++) mx = fmaxf(mx, pv[e]);
      mx = fmaxf(mx, __shfl_xor(mx, 16));
      mx = fmaxf(mx, __shfl_xor(mx, 32));
      if (__any(mx > mi0 + 11.5f)) {
        float mn = fmaxf(mi0, mx);
        float al = fexp2(mi0 - mn);
        li0 *= al;
#pragma unroll
        for (int dn = 0; dn < 4; dn++) {
          od0[dn][0] *= al; od0[dn][1] *= al; od0[dn][2] *= al; od0[dn][3] *= al;
        }
        mi0 = mn;
      }
      float ps = 0.f;
#pragma unroll
      for (int e = 0; e < 16; e++) {
        pv[e] = fexp2(pv[e] - mi0);
        ps += pv[e];
      }
      ps += __shfl_xor(ps, 16);
      ps += __shfl_xor(ps, 32);
      li0 += ps;
#pragma unroll
      for (int kn = 0; kn < 4; kn++) {
        unsigned int u0, u1;
        asm("v_cvt_pk_bf16_f32 %0, %1, %2" : "=v"(u0) : "v"(pv[kn * 4 + 0]), "v"(pv[kn * 4 + 1]));
        asm("v_cvt_pk_bf16_f32 %0, %1, %2" : "=v"(u1) : "v"(pv[kn * 4 + 2]), "v"(pv[kn * 4 + 3]));
        uint2 uu; uu.x = u0; uu.y = u1;
        *(uint2*)(Pw + lr * 128 + ((kn * 32 + quad * 8) ^ sw)) = uu;
      }
    }
    // ---- Q1: QK -> softmax -> P store ----
    {
      floatx4 sc[4];
      __builtin_amdgcn_s_setprio(1);
#pragma unroll
      for (int kn = 0; kn < 4; kn++) {
        short8 k0 = *(const short8*)(Kb + (kn * 16 + lr) * 128 + ro0);
        short8 k1 = *(const short8*)(Kb + (kn * 16 + lr) * 128 + ro1);
        floatx4 c = {};
        c = __builtin_amdgcn_mfma_f32_16x16x32_bf16(k0, a10, c, 0, 0, 0);
        c = __builtin_amdgcn_mfma_f32_16x16x32_bf16(k1, a11, c, 0, 0, 0);
        sc[kn] = c;
      }
      __builtin_amdgcn_s_setprio(0);
      float pv[16];
#pragma unroll
      for (int kn = 0; kn < 4; kn++)
#pragma unroll
        for (int r = 0; r < 4; r++) pv[kn * 4 + r] = sc[kn][r];
      if (skip0) {  // Q1 diagonal tile
#pragma unroll
        for (int e = 0; e < 16; e++) {
          int kg = t * 64 + (e >> 2) * 16 + quad * 4 + (e & 3);
          if (kg > qg1) pv[e] = -INFINITY;
        }
      }
      float mx = pv[0];
#pragma unroll
      for (int e = 1; e < 16; e++) mx = fmaxf(mx, pv[e]);
      mx = fmaxf(mx, __shfl_xor(mx, 16));
      mx = fmaxf(mx, __shfl_xor(mx, 32));
      if (__any(mx > mi1 + 11.5f)) {
        float mn = fmaxf(mi1, mx);
        float al = fexp2(mi1 - mn);
        li1 *= al;
#pragma unroll
        for (int dn = 0; dn < 4; dn++) {
          od1[dn][0] *= al; od1[dn][1] *= al; od1[dn][2] *= al; od1[dn][3] *= al;
        }
        mi1 = mn;
      }
      float ps = 0.f;
#pragma unroll
      for (int e = 0; e < 16; e++) {
        pv[e] = fexp2(pv[e] - mi1);
        ps += pv[e];
      }
      ps += __shfl_xor(ps, 16);
      ps += __shfl_xor(ps, 32);
      li1 += ps;
#pragma unroll
      for (int kn = 0; kn < 4; kn++) {
        unsigned int u0, u1;
        asm("v_cvt_pk_bf16_f32 %0, %1, %2" : "=v"(u0) : "v"(pv[kn * 4 + 0]), "v"(pv[kn * 4 + 1]));
        asm("v_cvt_pk_bf16_f32 %0, %1, %2" : "=v"(u1) : "v"(pv[kn * 4 + 2]), "v"(pv[kn * 4 + 3]));
        uint2 uu; uu.x = u0; uu.y = u1;
        *(uint2*)(Pw + 2048 + lr * 128 + ((kn * 32 + quad * 8) ^ sw)) = uu;
      }
    }
    // ---- PV for both frags ----
    __builtin_amdgcn_s_setprio(1);
    if (!skip0) {
      short8 pb0 = *(const short8*)(Pw + lr * 128 + ro0);
      short8 pb1 = *(const short8*)(Pw + lr * 128 + ro1);
#pragma unroll
      for (int dn = 0; dn < 4; dn++) {
        short8 va = *(const short8*)(Vb + (dn * 16 + lr) * 128 + ro0);
        short8 vb = *(const short8*)(Vb + (dn * 16 + lr) * 128 + ro1);
        od0[dn] = __builtin_amdgcn_mfma_f32_16x16x32_bf16(va, pb0, od0[dn], 0, 0, 0);
        od0[dn] = __builtin_amdgcn_mfma_f32_16x16x32_bf16(vb, pb1, od0[dn], 0, 0, 0);
      }
    }
    {
      short8 pb0 = *(const short8*)(Pw + 2048 + lr * 128 + ro0);
      short8 pb1 = *(const short8*)(Pw + 2048 + lr * 128 + ro1);
#pragma unroll
      for (int dn = 0; dn < 4; dn++) {
        short8 va = *(const short8*)(Vb + (dn * 16 + lr) * 128 + ro0);
        short8 vb = *(const short8*)(Vb + (dn * 16 + lr) * 128 + ro1);
        od1[dn] = __builtin_amdgcn_mfma_f32_16x16x32_bf16(va, pb0, od1[dn], 0, 0, 0);
        od1[dn] = __builtin_amdgcn_mfma_f32_16x16x32_bf16(vb, pb1, od1[dn], 0, 0, 0);
      }
    }
    __builtin_amdgcn_s_setprio(0);
    asm volatile("s_waitcnt vmcnt(0)" ::: "memory");
    __syncthreads();
    cur ^= 1;
  }
  float inv0 = 1.f / li0, inv1 = 1.f / li1;
  ushort_t* outp0 = q + ((size_t)(b * S_ + qg0) * NH + h) * HD;
  ushort_t* outp1 = q + ((size_t)(b * S_ + qg1) * NH + h) * HD;
#pragma unroll
  for (int dn = 0; dn < 4; dn++) {
    short4v u;
    u[0] = (short)f2bf(od0[dn][0] * inv0); u[1] = (short)f2bf(od0[dn][1] * inv0);
    u[2] = (short)f2bf(od0[dn][2] * inv0); u[3] = (short)f2bf(od0[dn][3] * inv0);
    *(short4v*)(outp0 + dn * 16 + quad * 4) = u;
    short4v v;
    v[0] = (short)f2bf(od1[dn][0] * inv1); v[1] = (short)f2bf(od1[dn][1] * inv1);
    v[2] = (short)f2bf(od1[dn][2] * inv1); v[3] = (short)f2bf(od1[dn][3] * inv1);
    *(short4v*)(outp1 + dn * 16 + quad * 4) = v;
  }
}

extern "C" void kernel_launch(void* const* d_in, const int* in_sizes, int n_in,
                              void* d_out, int out_size, void* d_ws, size_t ws_size,
                              hipStream_t stream) {
  const float* x = (const float*)d_in[0];
  const float* cosT = (const float*)d_in[2];
  const float* sinT = (const float*)d_in[3];
  const float* Wq = (const float*)d_in[4];
  const float* Wk = (const float*)d_in[5];
  const float* Wv = (const float*)d_in[6];
  const float* Wo = (const float*)d_in[7];

  char* ws = (char*)d_ws;
  ushort_t* WT = (ushort_t*)(ws);                 // 12 MB (3072, 2048): Wq^T | Wk^T | Wv^T
  ushort_t* WoT = (ushort_t*)(ws + 12582912);     //  8 MB (2048, 2048)
  ushort_t* xb = (ushort_t*)(ws + 20971520);      // 16 MB (M, 2048) bf16
  ushort_t* qbf = (ushort_t*)(ws + 37748736);     // 16 MB (B,S,NH,HD); ctx in-place
  ushort_t* kbf = (ushort_t*)(ws + 54525952);     //  4 MB (B,NKV,S,HD) swizzled
  ushort_t* vt = (ushort_t*)(ws + 58720256);      //  4 MB tiled (bg,S/64,HD,64) swizzled

  float* y = (float*)d_out;                            // (B,S,E) fp32
  float* outk = y + (size_t)M_ * E_;                   // (B,NKV,S,HD) fp32
  float* outv = outk + (size_t)B_ * NKV * S_ * HD;     // (B,NKV,S,HD) fp32

  prep<<<dim3(14336), 256, 0, stream>>>(x, xb, Wq, Wk, Wv, Wo, WT, WoT);

  gemm_qkv<<<dim3(192), 512, 0, stream>>>(xb, WT, qbf, outk, kbf, outv, vt, cosT, sinT);

  attn2<<<dim3(64, 16), 256, 0, stream>>>(qbf, kbf, vt);

  gemm_o<<<dim3(16, 32), 256, 0, stream>>>(qbf, WoT, y);
}